// Round 18
// baseline (1598.383 us; speedup 1.0000x reference)
//
#include <hip/hip_runtime.h>
#include <hip/hip_bf16.h>

#define BB 8
#define SS 512
#define CC 768
#define HH 12
#define HD 64
#define EE 8
#define KK 2
#define MLPH 3072
#define NT (BB*SS)
#define NOUT (NT*CC)

#define SLOTB      68059136ull
#define SLOT_U16   34029568ull
#define SLOT_F32   17014784ull

typedef unsigned int u32;
typedef unsigned short u16;
typedef __attribute__((ext_vector_type(8))) short short8;
typedef __attribute__((ext_vector_type(4))) float f32x4;

__device__ __forceinline__ u16 f2bf(float f) {
    u32 u = __builtin_bit_cast(u32, f);
    u32 r = (u + 0x7fffu + ((u >> 16) & 1u)) >> 16;
    return (u16)r;
}
__device__ __forceinline__ float bf2f(u16 h) {
    u32 u = ((u32)h) << 16;
    return __builtin_bit_cast(float, u);
}
__device__ __forceinline__ void gl_lds16(const void* g, void* l) {
    __builtin_amdgcn_global_load_lds(
        (const __attribute__((address_space(1))) u32*)g,
        (__attribute__((address_space(3))) u32*)l, 16, 0, 0);
}
// XCD-band mapping: each XCD owns 4 consecutive row-blocks; col-major in band.
__device__ __forceinline__ void swz_rc(int bid, int& bm, int& bn) {
    int xcd = bid & 7, off = bid >> 3;
    bm = (xcd * 4 + (off & 3)) * 128;
    bn = (off >> 2) * 128;
}

// deep-pipe staging: one 128x32 A-tile + one 128x32 B-tile; 4 vmem instr per wave
__device__ __forceinline__ void stg_dp2(const u16* __restrict__ A, const u16* __restrict__ B,
                                        int ldk, int koff, u16* sA, u16* sB, int tid)
{
    int wid = tid >> 6, lane = tid & 63;
#pragma unroll
    for (int rd = 0; rd < 2; rd++) {
        int cb = rd * 256 + wid * 64;
        int c = cb + lane;
        gl_lds16(A + (size_t)(c >> 2) * ldk + koff + (c & 3) * 8, sA + cb * 8);
    }
#pragma unroll
    for (int rd = 0; rd < 2; rd++) {
        int cb = rd * 256 + wid * 64;
        int c = cb + lane;
        gl_lds16(B + (size_t)(c >> 2) * ldk + koff + (c & 3) * 8, sB + cb * 8);
    }
}

// ---------------- Router ----------------
__global__ __launch_bounds__(256) void router_kernel(const float* __restrict__ x,
    const float* __restrict__ et, float* __restrict__ W, float* __restrict__ stats)
{
    __shared__ float etl[EE * CC];
    __shared__ float pred[4][2 * EE];
    int tid = threadIdx.x;
    for (int i = tid; i < EE * CC; i += 256) etl[i] = et[i];
    __syncthreads();
    int wid = tid >> 6, lane = tid & 63;
    float psum[EE] = {}, csum[EE] = {};
    for (int i = 0; i < 2; i++) {
        int t = blockIdx.x * 8 + wid * 2 + i;
        const float* xr = x + (size_t)t * CC;
        float acc[EE] = {};
        for (int c = lane; c < CC; c += 64) {
            float xv = xr[c];
#pragma unroll
            for (int e = 0; e < EE; e++) acc[e] += xv * etl[e * CC + c];
        }
#pragma unroll
        for (int e = 0; e < EE; e++)
            for (int off = 1; off < 64; off <<= 1) acc[e] += __shfl_xor(acc[e], off, 64);
        if (lane == 0) {
            const float inv = 0.03608439182435161f;
            float l[EE], m = -1e30f;
#pragma unroll
            for (int e = 0; e < EE; e++) { l[e] = acc[e] * inv; m = fmaxf(m, l[e]); }
            float p[EE], sum = 0.f;
#pragma unroll
            for (int e = 0; e < EE; e++) { p[e] = __expf(l[e] - m); sum += p[e]; }
            int i1 = 0;
#pragma unroll
            for (int e = 1; e < EE; e++) if (p[e] > p[i1]) i1 = e;
            int i2 = -1;
#pragma unroll
            for (int e = 0; e < EE; e++) if (e != i1 && (i2 < 0 || p[e] > p[i2])) i2 = e;
            float wn = p[i1] + p[i2];
#pragma unroll
            for (int e = 0; e < EE; e++) W[t * EE + e] = 0.f;
            W[t * EE + i1] = p[i1] / wn;
            W[t * EE + i2] = p[i2] / wn;
#pragma unroll
            for (int e = 0; e < EE; e++) psum[e] += p[e] / sum;
            csum[i1] += 1.f; csum[i2] += 1.f;
        }
    }
    if (lane == 0) {
#pragma unroll
        for (int e = 0; e < EE; e++) { pred[wid][e] = psum[e]; pred[wid][EE + e] = csum[e]; }
    }
    __syncthreads();
    if (tid < 2 * EE) {
        float s = pred[0][tid] + pred[1][tid] + pred[2][tid] + pred[3][tid];
        atomicAdd(&stats[tid], s);
    }
}

// ---------------- plain LayerNorm (affine folded), batched over y ----------------
template<int MODE>
__global__ __launch_bounds__(256) void ln_kernel(const float* __restrict__ x, size_t xslot,
    u16* __restrict__ out_hi, u16* __restrict__ out_lo, size_t oslot)
{
    int t = blockIdx.x;
    int eb = blockIdx.y;
    const float* xr = x + (size_t)eb * xslot + (size_t)t * CC;
    __shared__ float red[256];
    int tid = threadIdx.x;
    float v[3];
    float s = 0.f;
#pragma unroll
    for (int i = 0; i < 3; i++) { v[i] = xr[tid + i * 256]; s += v[i]; }
    red[tid] = s; __syncthreads();
    for (int off = 128; off > 0; off >>= 1) { if (tid < off) red[tid] += red[tid + off]; __syncthreads(); }
    float mu = red[0] / (float)CC;
    __syncthreads();
    float s2 = 0.f;
#pragma unroll
    for (int i = 0; i < 3; i++) { float d = v[i] - mu; s2 += d * d; }
    red[tid] = s2; __syncthreads();
    for (int off = 128; off > 0; off >>= 1) { if (tid < off) red[tid] += red[tid + off]; __syncthreads(); }
    float var = red[0] / (float)CC;
    float sc = rsqrtf(var + 1e-5f);
#pragma unroll
    for (int i = 0; i < 3; i++) {
        int c = tid + i * 256;
        float val = (v[i] - mu) * sc;
        u16 hi = f2bf(val);
        out_hi[(size_t)eb * oslot + (size_t)t * CC + c] = hi;
        if (MODE) out_lo[(size_t)eb * oslot + (size_t)t * CC + c] = f2bf(val - bf2f(hi));
    }
}

// ---------------- per-expert weight prep, batched over y ----------------
__global__ __launch_bounds__(256) void prep_expert(
    const float* __restrict__ qkv_w0, const float* __restrict__ qkv_b0,
    const float* __restrict__ proj_w0,
    const float* __restrict__ fc1_w0, const float* __restrict__ fc1_b0,
    const float* __restrict__ fc2_w0,
    const float* __restrict__ g1_0, const float* __restrict__ b1_0,
    const float* __restrict__ g2_0, const float* __restrict__ b2_0,
    u16* __restrict__ qkvTh, u16* __restrict__ qkvTl,
    u16* __restrict__ projT, u16* __restrict__ fc1T, u16* __restrict__ fc2T,
    float* __restrict__ biasq, float* __restrict__ biasf1, int ebase)
{
    __shared__ float tile[32][33];
    __shared__ float bsh[CC];
    __shared__ float redg[256];
    int bid = blockIdx.x;
    int eb = blockIdx.y;
    int ge = ebase + eb;
    int tid = threadIdx.x;
    const float* qkv_w = qkv_w0 + (size_t)ge * CC * 3 * CC;
    const float* qkv_b = qkv_b0 + (size_t)ge * 3 * CC;
    const float* proj_w = proj_w0 + (size_t)ge * CC * CC;
    const float* fc1_w = fc1_w0 + (size_t)ge * CC * MLPH;
    const float* fc1_b = fc1_b0 + (size_t)ge * MLPH;
    const float* fc2_w = fc2_w0 + (size_t)ge * MLPH * CC;
    const float* g1 = g1_0 + (size_t)ge * CC;
    const float* b1 = b1_0 + (size_t)ge * CC;
    const float* g2 = g2_0 + (size_t)ge * CC;
    const float* b2 = b2_0 + (size_t)ge * CC;

    if (bid < 6912) {
        const float* src; const float* scale = nullptr;
        u16 *dh, *dl = nullptr; int N, Kd, n0, k0;
        if (bid < 1728) {
            src = qkv_w; scale = g1;
            dh = qkvTh + (size_t)eb * SLOT_U16; dl = qkvTl + (size_t)eb * SLOT_U16;
            N = 2304; Kd = 768; n0 = (bid % 72) * 32; k0 = (bid / 72) * 32;
        } else if (bid < 2304) {
            int i = bid - 1728;
            src = proj_w; dh = projT + (size_t)eb * SLOT_U16; N = 768; Kd = 768;
            n0 = (i % 24) * 32; k0 = (i / 24) * 32;
        } else if (bid < 4608) {
            int i = bid - 2304;
            src = fc1_w; scale = g2; dh = fc1T + (size_t)eb * SLOT_U16; N = 3072; Kd = 768;
            n0 = (i % 96) * 32; k0 = (i / 96) * 32;
        } else {
            int i = bid - 4608;
            src = fc2_w; dh = fc2T + (size_t)eb * SLOT_U16; N = 768; Kd = 3072;
            n0 = (i % 24) * 32; k0 = (i / 24) * 32;
        }
        int tx = tid & 31, ty = tid >> 5;
#pragma unroll
        for (int i = 0; i < 32; i += 8) {
            float v = src[(size_t)(k0 + ty + i) * N + n0 + tx];
            if (scale) v *= scale[k0 + ty + i];
            tile[ty + i][tx] = v;
        }
        __syncthreads();
#pragma unroll
        for (int i = 0; i < 32; i += 8) {
            float v = tile[tx][ty + i];
            u16 hi = f2bf(v);
            dh[(size_t)(n0 + ty + i) * Kd + k0 + tx] = hi;
            if (dl) dl[(size_t)(n0 + ty + i) * Kd + k0 + tx] = f2bf(v - bf2f(hi));
        }
    } else {
        const float* bv; const float* wsrc; const float* badd;
        float* dst; int N, n0;
        if (bid < 6984) { bv = b1; wsrc = qkv_w; badd = qkv_b; dst = biasq + (size_t)eb * SLOT_F32; N = 2304; n0 = (bid - 6912) * 32; }
        else            { bv = b2; wsrc = fc1_w; badd = fc1_b; dst = biasf1 + (size_t)eb * SLOT_F32; N = MLPH; n0 = (bid - 6984) * 32; }
        for (int i = tid; i < CC; i += 256) bsh[i] = bv[i];
        __syncthreads();
        int g = tid & 31, l8 = tid >> 5;
        int n = n0 + g;
        float acc = 0.f;
        for (int k = l8; k < CC; k += 8) acc += bsh[k] * wsrc[(size_t)k * N + n];
        redg[tid] = acc; __syncthreads();
        if (tid < 32) {
            float sum = 0.f;
#pragma unroll
            for (int i = 0; i < 8; i++) sum += redg[tid + i * 32];
            dst[n0 + tid] = sum + badd[n0 + tid];
        }
    }
}

// ---------------- qk deep-pipe: virtual K=2304 over plane pairs, 128x128, BK=32, 3-buf ----------------
// tiles 0-23: Ah x Bh ; 24-47: Ah x Bl ; 48-71: Al x Bh.  Epilogue: hi/lo split write.
__global__ __launch_bounds__(256) void gemm_qk_dp(
    const u16* __restrict__ Ah, const u16* __restrict__ Al,
    const u16* __restrict__ Bh0, const u16* __restrict__ Bl0,
    const float* __restrict__ biasq0, u16* __restrict__ qk_hi0,
    u16* __restrict__ qk_lo0)
{
    __shared__ __align__(16) u16 sA[3][128 * 32];
    __shared__ __align__(16) u16 sB[3][128 * 32];
    const int NTILE = 72;
    int tid = threadIdx.x;
    int eb = blockIdx.y;
    int bm, bn;
    swz_rc(blockIdx.x, bm, bn);          // 384 blocks: 32 m x 12 n
    int wid = tid >> 6, lane = tid & 63;
    int wr = wid >> 1, wc = wid & 1;
    int la = lane & 15, lb = lane >> 4;

    const u16* Ahb = Ah + (size_t)bm * CC;
    const u16* Alb = Al + (size_t)bm * CC;
    const u16* Bhb = Bh0 + (size_t)eb * SLOT_U16 + (size_t)bn * CC;
    const u16* Blb = Bl0 + (size_t)eb * SLOT_U16 + (size_t)bn * CC;

    auto STG = [&](int s, int t) {
        int tt = (t < 24) ? t : (t < 48 ? t - 24 : t - 48);
        const u16* Ap = (t < 48) ? Ahb : Alb;
        const u16* Bp = (t < 24) ? Bhb : (t < 48 ? Blb : Bhb);
        stg_dp2(Ap, Bp, CC, tt * 32, sA[s], sB[s], tid);
    };

    f32x4 acc[4][4];
#pragma unroll
    for (int i = 0; i < 4; i++)
#pragma unroll
        for (int j = 0; j < 4; j++) acc[i][j] = (f32x4){0.f, 0.f, 0.f, 0.f};

    STG(0, 0);
    STG(1, 1);

    for (int t = 0; t < NTILE; t++) {
        if (t < NTILE - 1) asm volatile("s_waitcnt vmcnt(4)" ::: "memory");
        else               asm volatile("s_waitcnt vmcnt(0)" ::: "memory");
        __builtin_amdgcn_s_barrier();
        asm volatile("" ::: "memory");

        const u16* cA = &sA[t % 3][0];
        const u16* cB = &sB[t % 3][0];
        __builtin_amdgcn_s_setprio(1);
        short8 bv[4];
#pragma unroll
        for (int j = 0; j < 4; j++)
            bv[j] = *(const short8*)(cB + ((size_t)(wc * 64 + j * 16 + la) * 4 + lb) * 8);
#pragma unroll
        for (int i = 0; i < 4; i++) {
            short8 av = *(const short8*)(cA + ((size_t)(wr * 64 + i * 16 + la) * 4 + lb) * 8);
#pragma unroll
            for (int j = 0; j < 4; j++)
                acc[i][j] = __builtin_amdgcn_mfma_f32_16x16x32_bf16(av, bv[j], acc[i][j], 0, 0, 0);
        }
        __builtin_amdgcn_s_setprio(0);

        if (t + 2 < NTILE) STG((t + 2) % 3, t + 2);
    }

    const float* bias = biasq0 + (size_t)eb * SLOT_F32;
    u16* qk_hi = qk_hi0 + (size_t)eb * SLOT_U16;
    u16* qk_lo = qk_lo0 + (size_t)eb * SLOT_U16;
#pragma unroll
    for (int i = 0; i < 4; i++) {
#pragma unroll
        for (int j = 0; j < 4; j++) {
            int gn = bn + wc * 64 + j * 16 + la;
            float bsv = bias[gn];
#pragma unroll
            for (int r = 0; r < 4; r++) {
                int gm = bm + wr * 64 + i * 16 + lb * 4 + r;
                float v = acc[i][j][r] + bsv;
                u16 hi = f2bf(v);
                qk_hi[(size_t)gm * 1536 + gn] = hi;
                qk_lo[(size_t)gm * 1536 + gn] = f2bf(v - bf2f(hi));
            }
        }
    }
}

// ---------------- deep-pipe GEMM body: 128x128, BK=32, 3-buf, counted vmcnt ----------------
// EPI 1: C(f32)=res+AB+bias   EPI 2: C(bf16)=gelu(AB+bias)
// EPI 5: atomicAdd combine    EPI 7: C(bf16)=AB+bias
template<int EPI>
__device__ __forceinline__ void gemm_dp_body(
    const u16* __restrict__ Ab, const u16* __restrict__ Bb, int Kdim,
    const float* __restrict__ biasp, const float* __restrict__ resp,
    const float* __restrict__ Wt, int ge, const float* __restrict__ xinit,
    void* __restrict__ Cout, int N, int bm, int bn)
{
    __shared__ __align__(16) u16 sA[3][128 * 32];
    __shared__ __align__(16) u16 sB[3][128 * 32];
    int tid = threadIdx.x;
    int wid = tid >> 6, lane = tid & 63;
    int wr = wid >> 1, wc = wid & 1;
    int la = lane & 15, lb = lane >> 4;
    int NTILE = Kdim / 32;

    f32x4 acc[4][4];
#pragma unroll
    for (int i = 0; i < 4; i++)
#pragma unroll
        for (int j = 0; j < 4; j++) acc[i][j] = (f32x4){0.f, 0.f, 0.f, 0.f};

    stg_dp2(Ab, Bb, Kdim, 0, sA[0], sB[0], tid);
    stg_dp2(Ab, Bb, Kdim, 32, sA[1], sB[1], tid);

    for (int t = 0; t < NTILE; t++) {
        if (t < NTILE - 1) asm volatile("s_waitcnt vmcnt(4)" ::: "memory");
        else               asm volatile("s_waitcnt vmcnt(0)" ::: "memory");
        __builtin_amdgcn_s_barrier();
        asm volatile("" ::: "memory");

        const u16* cA = &sA[t % 3][0];
        const u16* cB = &sB[t % 3][0];
        __builtin_amdgcn_s_setprio(1);
        short8 bv[4];
#pragma unroll
        for (int j = 0; j < 4; j++)
            bv[j] = *(const short8*)(cB + ((size_t)(wc * 64 + j * 16 + la) * 4 + lb) * 8);
#pragma unroll
        for (int i = 0; i < 4; i++) {
            short8 av = *(const short8*)(cA + ((size_t)(wr * 64 + i * 16 + la) * 4 + lb) * 8);
#pragma unroll
            for (int j = 0; j < 4; j++)
                acc[i][j] = __builtin_amdgcn_mfma_f32_16x16x32_bf16(av, bv[j], acc[i][j], 0, 0, 0);
        }
        __builtin_amdgcn_s_setprio(0);

        if (t + 2 < NTILE) stg_dp2(Ab, Bb, Kdim, (t + 2) * 32, sA[(t + 2) % 3], sB[(t + 2) % 3], tid);
    }

#pragma unroll
    for (int i = 0; i < 4; i++) {
#pragma unroll
        for (int j = 0; j < 4; j++) {
            int gn = bn + wc * 64 + j * 16 + la;
            float bsv = biasp[gn];
#pragma unroll
            for (int r = 0; r < 4; r++) {
                int gm = bm + wr * 64 + i * 16 + lb * 4 + r;
                size_t idx = (size_t)gm * N + gn;
                float v = acc[i][j][r] + bsv;
                if (EPI == 1) {
                    ((float*)Cout)[idx] = resp[idx] + v;
                } else if (EPI == 2) {
                    float gel = 0.5f * v * (1.0f + erff(v * 0.70710678118654752f));
                    ((u16*)Cout)[idx] = f2bf(gel);
                } else if (EPI == 7) {
                    ((u16*)Cout)[idx] = f2bf(v);
                } else {
                    float w = Wt[(size_t)gm * EE + ge];
                    float val = w * (v + resp[idx]);
                    if (ge == 0) val += xinit[idx];
                    atomicAdd(&((float*)Cout)[idx], val);
                }
            }
        }
    }
}

// v GEMM: A=xh_hi [4096][768], B = v-rows of qkvTh (rows 1536..2304) -> vraw bf16 [4096][768]
__global__ __launch_bounds__(256) void gemm_v_dp(
    const u16* __restrict__ A0, const u16* __restrict__ BT0,
    const float* __restrict__ biasq0, u16* __restrict__ C0)
{
    int eb = blockIdx.y;
    int bm, bn;
    swz_rc(blockIdx.x, bm, bn);
    gemm_dp_body<7>(A0 + (size_t)bm * CC,
                    BT0 + (size_t)eb * SLOT_U16 + (size_t)(1536 + bn) * CC, CC,
                    biasq0 + (size_t)eb * SLOT_F32 + 1536, nullptr, nullptr, 0, nullptr,
                    C0 + (size_t)eb * SLOT_U16, CC, bm, bn);
}

// proj: grid (192, EB)
__global__ __launch_bounds__(256) void gemm_proj_dp(
    const u16* __restrict__ A0, const u16* __restrict__ BT0,
    const float* __restrict__ bias0, const float* __restrict__ x,
    float* __restrict__ C0)
{
    int eb = blockIdx.y;
    int bm, bn;
    swz_rc(blockIdx.x, bm, bn);
    gemm_dp_body<1>(A0 + (size_t)eb * SLOT_U16 + (size_t)bm * CC,
                    BT0 + (size_t)eb * SLOT_U16 + (size_t)bn * CC, CC,
                    bias0 + (size_t)eb * CC, x, nullptr, 0, nullptr,
                    C0 + (size_t)eb * SLOT_F32, CC, bm, bn);
}

// fc1: grid (768, EB)
__global__ __launch_bounds__(256) void gemm_fc1_dp(
    const u16* __restrict__ A0, const u16* __restrict__ BT0,
    const float* __restrict__ bias0, u16* __restrict__ C0)
{
    int eb = blockIdx.y;
    int bm, bn;
    swz_rc(blockIdx.x, bm, bn);
    gemm_dp_body<2>(A0 + (size_t)eb * SLOT_U16 + (size_t)bm * CC,
                    BT0 + (size_t)eb * SLOT_U16 + (size_t)bn * CC, CC,
                    bias0 + (size_t)eb * SLOT_F32, nullptr, nullptr, 0, nullptr,
                    C0 + (size_t)eb * SLOT_U16, MLPH, bm, bn);
}

// fc2: grid (192, EB)
__global__ __launch_bounds__(256) void gemm_fc2_dp(
    const u16* __restrict__ A0, const u16* __restrict__ BT0,
    const float* __restrict__ bias0, const float* __restrict__ res0,
    const float* __restrict__ Wt, int ebase, const float* __restrict__ xinit,
    float* __restrict__ Cout)
{
    int eb = blockIdx.y;
    int bm, bn;
    swz_rc(blockIdx.x, bm, bn);
    gemm_dp_body<5>(A0 + (size_t)eb * SLOT_U16 + (size_t)bm * MLPH,
                    BT0 + (size_t)eb * SLOT_U16 + (size_t)bn * MLPH, MLPH,
                    bias0 + (size_t)eb * CC, res0 + (size_t)eb * SLOT_F32,
                    Wt, ebase + eb, xinit, Cout, CC, bm, bn);
}

// ---------------- V transpose: vraw [4096][768] -> vt [b*H+h][d][s] ----------------
__global__ __launch_bounds__(256) void vtrans(const u16* __restrict__ vraw0,
    u16* __restrict__ vt0)
{
    __shared__ u16 tile[64][65];
    int st = blockIdx.x;
    int h = blockIdx.y;
    int z = blockIdx.z;
    int b = z & (BB - 1), eb = z >> 3;
    const u16* vraw = vraw0 + (size_t)eb * SLOT_U16;
    u16* vt = vt0 + (size_t)eb * SLOT_U16;
    int tid = threadIdx.x;
    int row = tid >> 3, ch = tid & 7;
#pragma unroll
    for (int it = 0; it < 2; it++) {
        int s = it * 32 + row;
        const u16* src = vraw + (size_t)(b * SS + st * 64 + s) * CC + h * HD + ch * 8;
        short8 v = *(const short8*)src;
#pragma unroll
        for (int k = 0; k < 8; k++) tile[s][ch * 8 + k] = (u16)v[k];
    }
    __syncthreads();
#pragma unroll
    for (int it = 0; it < 2; it++) {
        int d = it * 32 + row;
        u16* dst = vt + ((size_t)((b * HH + h) * HD + d)) * SS + st * 64 + ch * 8;
        short8 v;
#pragma unroll
        for (int k = 0; k < 8; k++) v[k] = (short)tile[ch * 8 + k][d];
        *(short8*)dst = v;
    }
}

// ---------------- MFMA flash attention, split QK^T, single-buffer, batched ----------------
__global__ __launch_bounds__(256) void attn_mfma(const u16* __restrict__ qk_hi0,
    const u16* __restrict__ qk_lo0, const u16* __restrict__ vt0, u16* __restrict__ o0)
{
    int q0 = blockIdx.x * 64;
    int h = blockIdx.y;
    int z = blockIdx.z;
    int b = z & (BB - 1), eb = z >> 3;
    int tid = threadIdx.x, wid = tid >> 6, lane = tid & 63;
    int la = lane & 15, lb = lane >> 4;
    __shared__ __align__(16) u16 Ksh[64 * 64];
    __shared__ __align__(16) u16 Ksl[64 * 64];
    __shared__ __align__(16) u16 Vs[64 * 64];
    __shared__ __align__(16) u16 Ps[4][16 * 64];

    const u16* qk_hi = qk_hi0 + (size_t)eb * SLOT_U16;
    const u16* qk_lo = qk_lo0 + (size_t)eb * SLOT_U16;
    const u16* vt = vt0 + (size_t)eb * SLOT_U16;
    u16* o = o0 + (size_t)eb * SLOT_U16;

    short8 aqh[2], aql[2];
    {
        size_t qoff = (size_t)(b * SS + q0 + wid * 16 + la) * 1536 + h * HD;
#pragma unroll
        for (int kc = 0; kc < 2; kc++) {
            aqh[kc] = *(const short8*)(qk_hi + qoff + kc * 32 + lb * 8);
            aql[kc] = *(const short8*)(qk_lo + qoff + kc * 32 + lb * 8);
        }
    }
    const u16* kbh = qk_hi + (size_t)(b * SS) * 1536 + CC + h * HD;
    const u16* kbl = qk_lo + (size_t)(b * SS) * 1536 + CC + h * HD;
    const u16* vtbase = vt + (size_t)((b * HH + h) * HD) * SS;

    float m_r[4], l_r[4];
    f32x4 acc_o[4];
#pragma unroll
    for (int r = 0; r < 4; r++) { m_r[r] = -1e30f; l_r[r] = 0.f; }
#pragma unroll
    for (int d0 = 0; d0 < 4; d0++) acc_o[d0] = (f32x4){0.f, 0.f, 0.f, 0.f};

    for (int kt = 0; kt < SS; kt += 64) {
#pragma unroll
        for (int it = 0; it < 2; it++) {
            int base = it * 256 + wid * 64;
            int c = base + lane;
            int row = c >> 3;
            int gk = (c & 7) ^ (row & 7);
            gl_lds16(kbh + (size_t)(kt + row) * 1536 + gk * 8, Ksh + base * 8);
            gl_lds16(kbl + (size_t)(kt + row) * 1536 + gk * 8, Ksl + base * 8);
            gl_lds16(vtbase + (size_t)row * SS + kt + gk * 8, Vs + base * 8);
        }
        __syncthreads();

        f32x4 s4[4];
#pragma unroll
        for (int j = 0; j < 4; j++) s4[j] = (f32x4){0.f, 0.f, 0.f, 0.f};
#pragma unroll
        for (int kc = 0; kc < 2; kc++)
#pragma unroll
            for (int j = 0; j < 4; j++) {
                size_t off = (size_t)(j * 16 + la) * 64 + (((kc * 4 + lb) ^ (la & 7)) * 8);
                short8 bkh = *(const short8*)(Ksh + off);
                short8 bkl = *(const short8*)(Ksl + off);
                s4[j] = __builtin_amdgcn_mfma_f32_16x16x32_bf16(aqh[kc], bkh, s4[j], 0, 0, 0);
                s4[j] = __builtin_amdgcn_mfma_f32_16x16x32_bf16(aql[kc], bkh, s4[j], 0, 0, 0);
                s4[j] = __builtin_amdgcn_mfma_f32_16x16x32_bf16(aqh[kc], bkl, s4[j], 0, 0, 0);
            }
#pragma unroll
        for (int j = 0; j < 4; j++) s4[j] = s4[j] * 8.f;

#pragma unroll
        for (int r = 0; r < 4; r++) {
            float mx = fmaxf(fmaxf(s4[0][r], s4[1][r]), fmaxf(s4[2][r], s4[3][r]));
#pragma unroll
            for (int off = 1; off < 16; off <<= 1) mx = fmaxf(mx, __shfl_xor(mx, off, 64));
            float mn = fmaxf(m_r[r], mx);
            float corr = __expf(m_r[r] - mn);
            m_r[r] = mn;
            float rs = 0.f;
#pragma unroll
            for (int j = 0; j < 4; j++) {
                float p = __expf(s4[j][r] - mn);
                s4[j][r] = p; rs += p;
            }
#pragma unroll
            for (int off = 1; off < 16; off <<= 1) rs += __shfl_xor(rs, off, 64);
            l_r[r] = l_r[r] * corr + rs;
#pragma unroll
            for (int d0 = 0; d0 < 4; d0++) acc_o[d0][r] = acc_o[d0][r] * corr;
        }
#pragma unroll
        for (int j = 0; j < 4; j++)
#pragma unroll
            for (int r = 0; r < 4; r++) {
                int row = lb * 4 + r;
                int sg = (2 * j + (la >> 3)) ^ (row & 7);
                Ps[wid][row * 64 + sg * 8 + (la & 7)] = f2bf(s4[j][r]);
            }
        short8 pa[2];
#pragma unroll
        for (int kc = 0; kc < 2; kc++)
            pa[kc] = *(const short8*)(&Ps[wid][la * 64 + (((kc * 4 + lb) ^ (la & 7)) * 8)]);
#pragma unroll
        for (int d0 = 0; d0 < 4; d0++)
#pragma unroll
            for (int kc = 0; kc < 2; kc++) {
                short8 bv = *(const short8*)(&Vs[(d0 * 16 + la) * 64 + (((kc * 4 + lb) ^ (la & 7)) * 8)]);
                acc_o[d0] = __builtin_amdgcn_mfma_f32_16x16x32_bf16(pa[kc], bv, acc_o[d0], 0, 0, 0);
            }
        __syncthreads();
    }
#pragma unroll
    for (int r = 0; r < 4; r++) {
        float invl = 1.f / l_r[r];
        int tok = b * SS + q0 + wid * 16 + lb * 4 + r;
#pragma unroll
        for (int d0 = 0; d0 < 4; d0++)
            o[(size_t)tok * CC + h * HD + d0 * 16 + la] = f2bf(acc_o[d0][r] * invl);
    }
}

// ---------------- balance loss ----------------
__global__ __launch_bounds__(256) void loss_kernel(const float* __restrict__ et,
    const float* __restrict__ stats, float* __restrict__ out_loss)
{
    __shared__ float red[256];
    int tid = threadIdx.x;
    float s = 0.f;
    for (int i = tid; i < EE * CC; i += 256) { float v = et[i]; s += v * v; }
    red[tid] = s; __syncthreads();
    for (int off = 128; off > 0; off >>= 1) { if (tid < off) red[tid] += red[tid + off]; __syncthreads(); }
    if (tid == 0) {
        float bl = 0.f;
        for (int e = 0; e < EE; e++) {
            float f = stats[EE + e] / (float)(NT * KK);
            float P = stats[e] / (float)NT;
            bl += f * P;
        }
        *out_loss = (float)EE * bl + 0.01f * sqrtf(red[0]);
    }
}

extern "C" void kernel_launch(void* const* d_in, const int* in_sizes, int n_in,
                              void* d_out, int out_size, void* d_ws, size_t ws_size,
                              hipStream_t stream) {
    const float* x      = (const float*)d_in[0];
    const float* et     = (const float*)d_in[1];
    const float* ln1_g  = (const float*)d_in[2];
    const float* ln1_b  = (const float*)d_in[3];
    const float* qkv_w  = (const float*)d_in[4];
    const float* qkv_b  = (const float*)d_in[5];
    const float* proj_w = (const float*)d_in[6];
    const float* proj_b = (const float*)d_in[7];
    const float* ln2_g  = (const float*)d_in[8];
    const float* ln2_b  = (const float*)d_in[9];
    const float* fc1_w  = (const float*)d_in[10];
    const float* fc1_b  = (const float*)d_in[11];
    const float* fc2_w  = (const float*)d_in[12];
    const float* fc2_b  = (const float*)d_in[13];
    float* outp = (float*)d_out;
    char* base = (char*)d_ws;

    const size_t FIXED = 12714496;
    int EB = 1;
    if (ws_size >= FIXED + 8 * SLOTB) EB = 8;
    else if (ws_size >= FIXED + 4 * SLOTB) EB = 4;
    else if (ws_size >= FIXED + 2 * SLOTB) EB = 2;

    float* W      = (float*)(base);
    float* stats  = (float*)(base + 131072);
    u16*   xh_hi  = (u16*)  (base + 131584);
    u16*   xh_lo  = (u16*)  (base + 6423040);
    char* slot0 = base + FIXED;
    u16*   qkvTh  = (u16*)  (slot0);
    u16*   qkvTl  = (u16*)  (slot0 + 3538944);
    u16*   projT  = (u16*)  (slot0 + 7077888);
    u16*   fc1T   = (u16*)  (slot0 + 8257536);
    u16*   fc2T   = (u16*)  (slot0 + 12976128);
    float* biasq  = (float*)(slot0 + 17694720);
    float* biasf1 = (float*)(slot0 + 17711104);
    u16*   qk_hi  = (u16*)  (slot0 + 17727488);
    u16*   qk_lo  = (u16*)  (slot0 + 30310400);
    u16*   mlp1   = (u16*)  (slot0 + 17727488);   // aliases qk_hi+qk_lo (dead after attn)
    u16*   vtb    = (u16*)  (slot0 + 42893312);
    u16*   xmhat  = (u16*)  (slot0 + 42893312);   // aliases vt (dead after attn)
    u16*   obf    = (u16*)  (slot0 + 49184768);
    u16*   vraw   = obf;                          // aliases obf (dead before attn writes it)
    float* xmid   = (float*)(slot0 + 55476224);

    hipMemsetAsync(stats, 0, 16 * sizeof(float), stream);
    hipMemsetAsync(outp, 0, (size_t)NOUT * sizeof(float), stream);

    router_kernel<<<NT / 8, 256, 0, stream>>>(x, et, W, stats);
    ln_kernel<1><<<dim3(NT, 1), 256, 0, stream>>>(x, 0, xh_hi, xh_lo, 0);

    for (int ebase = 0; ebase < EE; ebase += EB) {
        prep_expert<<<dim3(7080, EB), 256, 0, stream>>>(
            qkv_w, qkv_b, proj_w, fc1_w, fc1_b, fc2_w,
            ln1_g, ln1_b, ln2_g, ln2_b,
            qkvTh, qkvTl, projT, fc1T, fc2T, biasq, biasf1, ebase);

        gemm_qk_dp<<<dim3(12 * 32, EB), 256, 0, stream>>>(
            xh_hi, xh_lo, qkvTh, qkvTl, biasq, qk_hi, qk_lo);

        gemm_v_dp<<<dim3(6 * 32, EB), 256, 0, stream>>>(xh_hi, qkvTh, biasq, vraw);

        vtrans<<<dim3(SS / 64, HH, BB * EB), 256, 0, stream>>>(vraw, vtb);

        attn_mfma<<<dim3(SS / 64, HH, BB * EB), 256, 0, stream>>>(qk_hi, qk_lo, vtb, obf);

        gemm_proj_dp<<<dim3(6 * 32, EB), 256, 0, stream>>>(
            obf, projT, proj_b + (size_t)ebase * CC, x, xmid);

        ln_kernel<0><<<dim3(NT, EB), 256, 0, stream>>>(xmid, SLOT_F32, xmhat, nullptr, SLOT_U16);

        gemm_fc1_dp<<<dim3(24 * 32, EB), 256, 0, stream>>>(xmhat, fc1T, biasf1, mlp1);

        gemm_fc2_dp<<<dim3(6 * 32, EB), 256, 0, stream>>>(
            mlp1, fc2T, fc2_b + (size_t)ebase * CC, xmid, W, ebase, x, outp);
    }

    loss_kernel<<<1, 256, 0, stream>>>(et, stats, outp + NOUT);
}

// Round 19
// 1594.841 us; speedup vs baseline: 1.0022x; 1.0022x over previous
//
#include <hip/hip_runtime.h>
#include <hip/hip_bf16.h>

#define BB 8
#define SS 512
#define CC 768
#define HH 12
#define HD 64
#define EE 8
#define KK 2
#define MLPH 3072
#define NT (BB*SS)
#define NOUT (NT*CC)

#define SLOTB      68059136ull
#define SLOT_U16   34029568ull
#define SLOT_F32   17014784ull

typedef unsigned int u32;
typedef unsigned short u16;
typedef __attribute__((ext_vector_type(8))) short short8;
typedef __attribute__((ext_vector_type(4))) float f32x4;

__device__ __forceinline__ u16 f2bf(float f) {
    u32 u = __builtin_bit_cast(u32, f);
    u32 r = (u + 0x7fffu + ((u >> 16) & 1u)) >> 16;
    return (u16)r;
}
__device__ __forceinline__ float bf2f(u16 h) {
    u32 u = ((u32)h) << 16;
    return __builtin_bit_cast(float, u);
}
__device__ __forceinline__ void gl_lds16(const void* g, void* l) {
    __builtin_amdgcn_global_load_lds(
        (const __attribute__((address_space(1))) u32*)g,
        (__attribute__((address_space(3))) u32*)l, 16, 0, 0);
}
// XCD-band mapping: each XCD owns 4 consecutive row-blocks; col-major in band.
__device__ __forceinline__ void swz_rc(int bid, int& bm, int& bn) {
    int xcd = bid & 7, off = bid >> 3;
    bm = (xcd * 4 + (off & 3)) * 128;
    bn = (off >> 2) * 128;
}

// packed-swizzle LDS index for a 128x32 bf16 tile stored as 64 lines x 8 slots(16B):
// logical row r, k-chunk lb(0..3) -> u16 offset
__device__ __forceinline__ size_t dpidx(int r, int lb) {
    int L = r >> 1;
    int slot = (((r & 1) << 2) | lb) ^ (L & 7);
    return (size_t)L * 64 + slot * 8;
}

// deep-pipe staging: one 128x32 A-tile + one 128x32 B-tile; 4 vmem instr per wave.
// LDS dest linear in chunk id c; global source pre-swizzled (m173) to realize dpidx layout.
__device__ __forceinline__ void stg_dp2(const u16* __restrict__ A, const u16* __restrict__ B,
                                        int ldk, int koff, u16* sA, u16* sB, int tid)
{
    int wid = tid >> 6, lane = tid & 63;
#pragma unroll
    for (int rd = 0; rd < 2; rd++) {
        int cb = rd * 256 + wid * 64;
        int c = cb + lane;
        int L = c >> 3, sp = c & 7;
        int slog = sp ^ (L & 7);
        int row = 2 * L + (slog >> 2), ch = slog & 3;
        gl_lds16(A + (size_t)row * ldk + koff + ch * 8, sA + (size_t)cb * 8);
    }
#pragma unroll
    for (int rd = 0; rd < 2; rd++) {
        int cb = rd * 256 + wid * 64;
        int c = cb + lane;
        int L = c >> 3, sp = c & 7;
        int slog = sp ^ (L & 7);
        int row = 2 * L + (slog >> 2), ch = slog & 3;
        gl_lds16(B + (size_t)row * ldk + koff + ch * 8, sB + (size_t)cb * 8);
    }
}

// ---------------- Router ----------------
__global__ __launch_bounds__(256) void router_kernel(const float* __restrict__ x,
    const float* __restrict__ et, float* __restrict__ W, float* __restrict__ stats)
{
    __shared__ float etl[EE * CC];
    __shared__ float pred[4][2 * EE];
    int tid = threadIdx.x;
    for (int i = tid; i < EE * CC; i += 256) etl[i] = et[i];
    __syncthreads();
    int wid = tid >> 6, lane = tid & 63;
    float psum[EE] = {}, csum[EE] = {};
    for (int i = 0; i < 2; i++) {
        int t = blockIdx.x * 8 + wid * 2 + i;
        const float* xr = x + (size_t)t * CC;
        float acc[EE] = {};
        for (int c = lane; c < CC; c += 64) {
            float xv = xr[c];
#pragma unroll
            for (int e = 0; e < EE; e++) acc[e] += xv * etl[e * CC + c];
        }
#pragma unroll
        for (int e = 0; e < EE; e++)
            for (int off = 1; off < 64; off <<= 1) acc[e] += __shfl_xor(acc[e], off, 64);
        if (lane == 0) {
            const float inv = 0.03608439182435161f;
            float l[EE], m = -1e30f;
#pragma unroll
            for (int e = 0; e < EE; e++) { l[e] = acc[e] * inv; m = fmaxf(m, l[e]); }
            float p[EE], sum = 0.f;
#pragma unroll
            for (int e = 0; e < EE; e++) { p[e] = __expf(l[e] - m); sum += p[e]; }
            int i1 = 0;
#pragma unroll
            for (int e = 1; e < EE; e++) if (p[e] > p[i1]) i1 = e;
            int i2 = -1;
#pragma unroll
            for (int e = 0; e < EE; e++) if (e != i1 && (i2 < 0 || p[e] > p[i2])) i2 = e;
            float wn = p[i1] + p[i2];
#pragma unroll
            for (int e = 0; e < EE; e++) W[t * EE + e] = 0.f;
            W[t * EE + i1] = p[i1] / wn;
            W[t * EE + i2] = p[i2] / wn;
#pragma unroll
            for (int e = 0; e < EE; e++) psum[e] += p[e] / sum;
            csum[i1] += 1.f; csum[i2] += 1.f;
        }
    }
    if (lane == 0) {
#pragma unroll
        for (int e = 0; e < EE; e++) { pred[wid][e] = psum[e]; pred[wid][EE + e] = csum[e]; }
    }
    __syncthreads();
    if (tid < 2 * EE) {
        float s = pred[0][tid] + pred[1][tid] + pred[2][tid] + pred[3][tid];
        atomicAdd(&stats[tid], s);
    }
}

// ---------------- plain LayerNorm (affine folded), batched over y ----------------
template<int MODE>
__global__ __launch_bounds__(256) void ln_kernel(const float* __restrict__ x, size_t xslot,
    u16* __restrict__ out_hi, u16* __restrict__ out_lo, size_t oslot)
{
    int t = blockIdx.x;
    int eb = blockIdx.y;
    const float* xr = x + (size_t)eb * xslot + (size_t)t * CC;
    __shared__ float red[256];
    int tid = threadIdx.x;
    float v[3];
    float s = 0.f;
#pragma unroll
    for (int i = 0; i < 3; i++) { v[i] = xr[tid + i * 256]; s += v[i]; }
    red[tid] = s; __syncthreads();
    for (int off = 128; off > 0; off >>= 1) { if (tid < off) red[tid] += red[tid + off]; __syncthreads(); }
    float mu = red[0] / (float)CC;
    __syncthreads();
    float s2 = 0.f;
#pragma unroll
    for (int i = 0; i < 3; i++) { float d = v[i] - mu; s2 += d * d; }
    red[tid] = s2; __syncthreads();
    for (int off = 128; off > 0; off >>= 1) { if (tid < off) red[tid] += red[tid + off]; __syncthreads(); }
    float var = red[0] / (float)CC;
    float sc = rsqrtf(var + 1e-5f);
#pragma unroll
    for (int i = 0; i < 3; i++) {
        int c = tid + i * 256;
        float val = (v[i] - mu) * sc;
        u16 hi = f2bf(val);
        out_hi[(size_t)eb * oslot + (size_t)t * CC + c] = hi;
        if (MODE) out_lo[(size_t)eb * oslot + (size_t)t * CC + c] = f2bf(val - bf2f(hi));
    }
}

// ---------------- per-expert weight prep, batched over y ----------------
__global__ __launch_bounds__(256) void prep_expert(
    const float* __restrict__ qkv_w0, const float* __restrict__ qkv_b0,
    const float* __restrict__ proj_w0,
    const float* __restrict__ fc1_w0, const float* __restrict__ fc1_b0,
    const float* __restrict__ fc2_w0,
    const float* __restrict__ g1_0, const float* __restrict__ b1_0,
    const float* __restrict__ g2_0, const float* __restrict__ b2_0,
    u16* __restrict__ qkvTh, u16* __restrict__ qkvTl,
    u16* __restrict__ projT, u16* __restrict__ fc1T, u16* __restrict__ fc2T,
    float* __restrict__ biasq, float* __restrict__ biasf1, int ebase)
{
    __shared__ float tile[32][33];
    __shared__ float bsh[CC];
    __shared__ float redg[256];
    int bid = blockIdx.x;
    int eb = blockIdx.y;
    int ge = ebase + eb;
    int tid = threadIdx.x;
    const float* qkv_w = qkv_w0 + (size_t)ge * CC * 3 * CC;
    const float* qkv_b = qkv_b0 + (size_t)ge * 3 * CC;
    const float* proj_w = proj_w0 + (size_t)ge * CC * CC;
    const float* fc1_w = fc1_w0 + (size_t)ge * CC * MLPH;
    const float* fc1_b = fc1_b0 + (size_t)ge * MLPH;
    const float* fc2_w = fc2_w0 + (size_t)ge * MLPH * CC;
    const float* g1 = g1_0 + (size_t)ge * CC;
    const float* b1 = b1_0 + (size_t)ge * CC;
    const float* g2 = g2_0 + (size_t)ge * CC;
    const float* b2 = b2_0 + (size_t)ge * CC;

    if (bid < 6912) {
        const float* src; const float* scale = nullptr;
        u16 *dh, *dl = nullptr; int N, Kd, n0, k0;
        if (bid < 1728) {
            src = qkv_w; scale = g1;
            dh = qkvTh + (size_t)eb * SLOT_U16; dl = qkvTl + (size_t)eb * SLOT_U16;
            N = 2304; Kd = 768; n0 = (bid % 72) * 32; k0 = (bid / 72) * 32;
        } else if (bid < 2304) {
            int i = bid - 1728;
            src = proj_w; dh = projT + (size_t)eb * SLOT_U16; N = 768; Kd = 768;
            n0 = (i % 24) * 32; k0 = (i / 24) * 32;
        } else if (bid < 4608) {
            int i = bid - 2304;
            src = fc1_w; scale = g2; dh = fc1T + (size_t)eb * SLOT_U16; N = 3072; Kd = 768;
            n0 = (i % 96) * 32; k0 = (i / 96) * 32;
        } else {
            int i = bid - 4608;
            src = fc2_w; dh = fc2T + (size_t)eb * SLOT_U16; N = 768; Kd = 3072;
            n0 = (i % 24) * 32; k0 = (i / 24) * 32;
        }
        int tx = tid & 31, ty = tid >> 5;
#pragma unroll
        for (int i = 0; i < 32; i += 8) {
            float v = src[(size_t)(k0 + ty + i) * N + n0 + tx];
            if (scale) v *= scale[k0 + ty + i];
            tile[ty + i][tx] = v;
        }
        __syncthreads();
#pragma unroll
        for (int i = 0; i < 32; i += 8) {
            float v = tile[tx][ty + i];
            u16 hi = f2bf(v);
            dh[(size_t)(n0 + ty + i) * Kd + k0 + tx] = hi;
            if (dl) dl[(size_t)(n0 + ty + i) * Kd + k0 + tx] = f2bf(v - bf2f(hi));
        }
    } else {
        const float* bv; const float* wsrc; const float* badd;
        float* dst; int N, n0;
        if (bid < 6984) { bv = b1; wsrc = qkv_w; badd = qkv_b; dst = biasq + (size_t)eb * SLOT_F32; N = 2304; n0 = (bid - 6912) * 32; }
        else            { bv = b2; wsrc = fc1_w; badd = fc1_b; dst = biasf1 + (size_t)eb * SLOT_F32; N = MLPH; n0 = (bid - 6984) * 32; }
        for (int i = tid; i < CC; i += 256) bsh[i] = bv[i];
        __syncthreads();
        int g = tid & 31, l8 = tid >> 5;
        int n = n0 + g;
        float acc = 0.f;
        for (int k = l8; k < CC; k += 8) acc += bsh[k] * wsrc[(size_t)k * N + n];
        redg[tid] = acc; __syncthreads();
        if (tid < 32) {
            float sum = 0.f;
#pragma unroll
            for (int i = 0; i < 8; i++) sum += redg[tid + i * 32];
            dst[n0 + tid] = sum + badd[n0 + tid];
        }
    }
}

// ---------------- qk deep-pipe: virtual K=2304 over plane pairs, 128x128, BK=32, 3-buf ----------------
__global__ __launch_bounds__(256) void gemm_qk_dp(
    const u16* __restrict__ Ah, const u16* __restrict__ Al,
    const u16* __restrict__ Bh0, const u16* __restrict__ Bl0,
    const float* __restrict__ biasq0, u16* __restrict__ qk_hi0,
    u16* __restrict__ qk_lo0)
{
    __shared__ __align__(16) u16 sA[3][128 * 32];
    __shared__ __align__(16) u16 sB[3][128 * 32];
    const int NTILE = 72;
    int tid = threadIdx.x;
    int eb = blockIdx.y;
    int bm, bn;
    swz_rc(blockIdx.x, bm, bn);          // 384 blocks: 32 m x 12 n
    int wid = tid >> 6, lane = tid & 63;
    int wr = wid >> 1, wc = wid & 1;
    int la = lane & 15, lb = lane >> 4;

    const u16* Ahb = Ah + (size_t)bm * CC;
    const u16* Alb = Al + (size_t)bm * CC;
    const u16* Bhb = Bh0 + (size_t)eb * SLOT_U16 + (size_t)bn * CC;
    const u16* Blb = Bl0 + (size_t)eb * SLOT_U16 + (size_t)bn * CC;

    auto STG = [&](int s, int t) {
        int tt = (t < 24) ? t : (t < 48 ? t - 24 : t - 48);
        const u16* Ap = (t < 48) ? Ahb : Alb;
        const u16* Bp = (t < 24) ? Bhb : (t < 48 ? Blb : Bhb);
        stg_dp2(Ap, Bp, CC, tt * 32, sA[s], sB[s], tid);
    };

    f32x4 acc[4][4];
#pragma unroll
    for (int i = 0; i < 4; i++)
#pragma unroll
        for (int j = 0; j < 4; j++) acc[i][j] = (f32x4){0.f, 0.f, 0.f, 0.f};

    STG(0, 0);
    STG(1, 1);

    for (int t = 0; t < NTILE; t++) {
        if (t < NTILE - 1) asm volatile("s_waitcnt vmcnt(4)" ::: "memory");
        else               asm volatile("s_waitcnt vmcnt(0)" ::: "memory");
        __builtin_amdgcn_s_barrier();
        asm volatile("" ::: "memory");

        const u16* cA = &sA[t % 3][0];
        const u16* cB = &sB[t % 3][0];
        __builtin_amdgcn_s_setprio(1);
        short8 bv[4];
#pragma unroll
        for (int j = 0; j < 4; j++)
            bv[j] = *(const short8*)(cB + dpidx(wc * 64 + j * 16 + la, lb));
#pragma unroll
        for (int i = 0; i < 4; i++) {
            short8 av = *(const short8*)(cA + dpidx(wr * 64 + i * 16 + la, lb));
#pragma unroll
            for (int j = 0; j < 4; j++)
                acc[i][j] = __builtin_amdgcn_mfma_f32_16x16x32_bf16(av, bv[j], acc[i][j], 0, 0, 0);
        }
        __builtin_amdgcn_s_setprio(0);

        if (t + 2 < NTILE) STG((t + 2) % 3, t + 2);
    }

    const float* bias = biasq0 + (size_t)eb * SLOT_F32;
    u16* qk_hi = qk_hi0 + (size_t)eb * SLOT_U16;
    u16* qk_lo = qk_lo0 + (size_t)eb * SLOT_U16;
#pragma unroll
    for (int i = 0; i < 4; i++) {
#pragma unroll
        for (int j = 0; j < 4; j++) {
            int gn = bn + wc * 64 + j * 16 + la;
            float bsv = bias[gn];
#pragma unroll
            for (int r = 0; r < 4; r++) {
                int gm = bm + wr * 64 + i * 16 + lb * 4 + r;
                float v = acc[i][j][r] + bsv;
                u16 hi = f2bf(v);
                qk_hi[(size_t)gm * 1536 + gn] = hi;
                qk_lo[(size_t)gm * 1536 + gn] = f2bf(v - bf2f(hi));
            }
        }
    }
}

// ---------------- deep-pipe GEMM body: 128x128, BK=32, 3-buf, counted vmcnt ----------------
// EPI 1: C(f32)=res+AB+bias   EPI 2: C(bf16)=gelu(AB+bias)
// EPI 5: atomicAdd combine    EPI 7: C(bf16)=AB+bias
template<int EPI>
__device__ __forceinline__ void gemm_dp_body(
    const u16* __restrict__ Ab, const u16* __restrict__ Bb, int Kdim,
    const float* __restrict__ biasp, const float* __restrict__ resp,
    const float* __restrict__ Wt, int ge, const float* __restrict__ xinit,
    void* __restrict__ Cout, int N, int bm, int bn)
{
    __shared__ __align__(16) u16 sA[3][128 * 32];
    __shared__ __align__(16) u16 sB[3][128 * 32];
    int tid = threadIdx.x;
    int wid = tid >> 6, lane = tid & 63;
    int wr = wid >> 1, wc = wid & 1;
    int la = lane & 15, lb = lane >> 4;
    int NTILE = Kdim / 32;

    f32x4 acc[4][4];
#pragma unroll
    for (int i = 0; i < 4; i++)
#pragma unroll
        for (int j = 0; j < 4; j++) acc[i][j] = (f32x4){0.f, 0.f, 0.f, 0.f};

    stg_dp2(Ab, Bb, Kdim, 0, sA[0], sB[0], tid);
    stg_dp2(Ab, Bb, Kdim, 32, sA[1], sB[1], tid);

    for (int t = 0; t < NTILE; t++) {
        if (t < NTILE - 1) asm volatile("s_waitcnt vmcnt(4)" ::: "memory");
        else               asm volatile("s_waitcnt vmcnt(0)" ::: "memory");
        __builtin_amdgcn_s_barrier();
        asm volatile("" ::: "memory");

        const u16* cA = &sA[t % 3][0];
        const u16* cB = &sB[t % 3][0];
        __builtin_amdgcn_s_setprio(1);
        short8 bv[4];
#pragma unroll
        for (int j = 0; j < 4; j++)
            bv[j] = *(const short8*)(cB + dpidx(wc * 64 + j * 16 + la, lb));
#pragma unroll
        for (int i = 0; i < 4; i++) {
            short8 av = *(const short8*)(cA + dpidx(wr * 64 + i * 16 + la, lb));
#pragma unroll
            for (int j = 0; j < 4; j++)
                acc[i][j] = __builtin_amdgcn_mfma_f32_16x16x32_bf16(av, bv[j], acc[i][j], 0, 0, 0);
        }
        __builtin_amdgcn_s_setprio(0);

        if (t + 2 < NTILE) stg_dp2(Ab, Bb, Kdim, (t + 2) * 32, sA[(t + 2) % 3], sB[(t + 2) % 3], tid);
    }

#pragma unroll
    for (int i = 0; i < 4; i++) {
#pragma unroll
        for (int j = 0; j < 4; j++) {
            int gn = bn + wc * 64 + j * 16 + la;
            float bsv = biasp[gn];
#pragma unroll
            for (int r = 0; r < 4; r++) {
                int gm = bm + wr * 64 + i * 16 + lb * 4 + r;
                size_t idx = (size_t)gm * N + gn;
                float v = acc[i][j][r] + bsv;
                if (EPI == 1) {
                    ((float*)Cout)[idx] = resp[idx] + v;
                } else if (EPI == 2) {
                    float gel = 0.5f * v * (1.0f + erff(v * 0.70710678118654752f));
                    ((u16*)Cout)[idx] = f2bf(gel);
                } else if (EPI == 7) {
                    ((u16*)Cout)[idx] = f2bf(v);
                } else {
                    float w = Wt[(size_t)gm * EE + ge];
                    float val = w * (v + resp[idx]);
                    if (ge == 0) val += xinit[idx];
                    atomicAdd(&((float*)Cout)[idx], val);
                }
            }
        }
    }
}

// v GEMM: A=xh_hi [4096][768], B = v-rows of qkvTh (rows 1536..2304) -> vraw bf16 [4096][768]
__global__ __launch_bounds__(256) void gemm_v_dp(
    const u16* __restrict__ A0, const u16* __restrict__ BT0,
    const float* __restrict__ biasq0, u16* __restrict__ C0)
{
    int eb = blockIdx.y;
    int bm, bn;
    swz_rc(blockIdx.x, bm, bn);
    gemm_dp_body<7>(A0 + (size_t)bm * CC,
                    BT0 + (size_t)eb * SLOT_U16 + (size_t)(1536 + bn) * CC, CC,
                    biasq0 + (size_t)eb * SLOT_F32 + 1536, nullptr, nullptr, 0, nullptr,
                    C0 + (size_t)eb * SLOT_U16, CC, bm, bn);
}

// proj: grid (192, EB)
__global__ __launch_bounds__(256) void gemm_proj_dp(
    const u16* __restrict__ A0, const u16* __restrict__ BT0,
    const float* __restrict__ bias0, const float* __restrict__ x,
    float* __restrict__ C0)
{
    int eb = blockIdx.y;
    int bm, bn;
    swz_rc(blockIdx.x, bm, bn);
    gemm_dp_body<1>(A0 + (size_t)eb * SLOT_U16 + (size_t)bm * CC,
                    BT0 + (size_t)eb * SLOT_U16 + (size_t)bn * CC, CC,
                    bias0 + (size_t)eb * CC, x, nullptr, 0, nullptr,
                    C0 + (size_t)eb * SLOT_F32, CC, bm, bn);
}

// fc1: grid (768, EB)
__global__ __launch_bounds__(256) void gemm_fc1_dp(
    const u16* __restrict__ A0, const u16* __restrict__ BT0,
    const float* __restrict__ bias0, u16* __restrict__ C0)
{
    int eb = blockIdx.y;
    int bm, bn;
    swz_rc(blockIdx.x, bm, bn);
    gemm_dp_body<2>(A0 + (size_t)eb * SLOT_U16 + (size_t)bm * CC,
                    BT0 + (size_t)eb * SLOT_U16 + (size_t)bn * CC, CC,
                    bias0 + (size_t)eb * SLOT_F32, nullptr, nullptr, 0, nullptr,
                    C0 + (size_t)eb * SLOT_U16, MLPH, bm, bn);
}

// fc2: grid (192, EB)
__global__ __launch_bounds__(256) void gemm_fc2_dp(
    const u16* __restrict__ A0, const u16* __restrict__ BT0,
    const float* __restrict__ bias0, const float* __restrict__ res0,
    const float* __restrict__ Wt, int ebase, const float* __restrict__ xinit,
    float* __restrict__ Cout)
{
    int eb = blockIdx.y;
    int bm, bn;
    swz_rc(blockIdx.x, bm, bn);
    gemm_dp_body<5>(A0 + (size_t)eb * SLOT_U16 + (size_t)bm * MLPH,
                    BT0 + (size_t)eb * SLOT_U16 + (size_t)bn * MLPH, MLPH,
                    bias0 + (size_t)eb * CC, res0 + (size_t)eb * SLOT_F32,
                    Wt, ebase + eb, xinit, Cout, CC, bm, bn);
}

// ---------------- V transpose: vraw [4096][768] -> vt [b*H+h][d][s] ----------------
__global__ __launch_bounds__(256) void vtrans(const u16* __restrict__ vraw0,
    u16* __restrict__ vt0)
{
    __shared__ u16 tile[64][65];
    int st = blockIdx.x;
    int h = blockIdx.y;
    int z = blockIdx.z;
    int b = z & (BB - 1), eb = z >> 3;
    const u16* vraw = vraw0 + (size_t)eb * SLOT_U16;
    u16* vt = vt0 + (size_t)eb * SLOT_U16;
    int tid = threadIdx.x;
    int row = tid >> 3, ch = tid & 7;
#pragma unroll
    for (int it = 0; it < 2; it++) {
        int s = it * 32 + row;
        const u16* src = vraw + (size_t)(b * SS + st * 64 + s) * CC + h * HD + ch * 8;
        short8 v = *(const short8*)src;
#pragma unroll
        for (int k = 0; k < 8; k++) tile[s][ch * 8 + k] = (u16)v[k];
    }
    __syncthreads();
#pragma unroll
    for (int it = 0; it < 2; it++) {
        int d = it * 32 + row;
        u16* dst = vt + ((size_t)((b * HH + h) * HD + d)) * SS + st * 64 + ch * 8;
        short8 v;
#pragma unroll
        for (int k = 0; k < 8; k++) v[k] = (short)tile[ch * 8 + k][d];
        *(short8*)dst = v;
    }
}

// ---------------- MFMA flash attention, split QK^T, single-buffer, batched ----------------
__global__ __launch_bounds__(256) void attn_mfma(const u16* __restrict__ qk_hi0,
    const u16* __restrict__ qk_lo0, const u16* __restrict__ vt0, u16* __restrict__ o0)
{
    int q0 = blockIdx.x * 64;
    int h = blockIdx.y;
    int z = blockIdx.z;
    int b = z & (BB - 1), eb = z >> 3;
    int tid = threadIdx.x, wid = tid >> 6, lane = tid & 63;
    int la = lane & 15, lb = lane >> 4;
    __shared__ __align__(16) u16 Ksh[64 * 64];
    __shared__ __align__(16) u16 Ksl[64 * 64];
    __shared__ __align__(16) u16 Vs[64 * 64];
    __shared__ __align__(16) u16 Ps[4][16 * 64];

    const u16* qk_hi = qk_hi0 + (size_t)eb * SLOT_U16;
    const u16* qk_lo = qk_lo0 + (size_t)eb * SLOT_U16;
    const u16* vt = vt0 + (size_t)eb * SLOT_U16;
    u16* o = o0 + (size_t)eb * SLOT_U16;

    short8 aqh[2], aql[2];
    {
        size_t qoff = (size_t)(b * SS + q0 + wid * 16 + la) * 1536 + h * HD;
#pragma unroll
        for (int kc = 0; kc < 2; kc++) {
            aqh[kc] = *(const short8*)(qk_hi + qoff + kc * 32 + lb * 8);
            aql[kc] = *(const short8*)(qk_lo + qoff + kc * 32 + lb * 8);
        }
    }
    const u16* kbh = qk_hi + (size_t)(b * SS) * 1536 + CC + h * HD;
    const u16* kbl = qk_lo + (size_t)(b * SS) * 1536 + CC + h * HD;
    const u16* vtbase = vt + (size_t)((b * HH + h) * HD) * SS;

    float m_r[4], l_r[4];
    f32x4 acc_o[4];
#pragma unroll
    for (int r = 0; r < 4; r++) { m_r[r] = -1e30f; l_r[r] = 0.f; }
#pragma unroll
    for (int d0 = 0; d0 < 4; d0++) acc_o[d0] = (f32x4){0.f, 0.f, 0.f, 0.f};

    for (int kt = 0; kt < SS; kt += 64) {
#pragma unroll
        for (int it = 0; it < 2; it++) {
            int base = it * 256 + wid * 64;
            int c = base + lane;
            int row = c >> 3;
            int gk = (c & 7) ^ (row & 7);
            gl_lds16(kbh + (size_t)(kt + row) * 1536 + gk * 8, Ksh + base * 8);
            gl_lds16(kbl + (size_t)(kt + row) * 1536 + gk * 8, Ksl + base * 8);
            gl_lds16(vtbase + (size_t)row * SS + kt + gk * 8, Vs + base * 8);
        }
        __syncthreads();

        f32x4 s4[4];
#pragma unroll
        for (int j = 0; j < 4; j++) s4[j] = (f32x4){0.f, 0.f, 0.f, 0.f};
#pragma unroll
        for (int kc = 0; kc < 2; kc++)
#pragma unroll
            for (int j = 0; j < 4; j++) {
                size_t off = (size_t)(j * 16 + la) * 64 + (((kc * 4 + lb) ^ (la & 7)) * 8);
                short8 bkh = *(const short8*)(Ksh + off);
                short8 bkl = *(const short8*)(Ksl + off);
                s4[j] = __builtin_amdgcn_mfma_f32_16x16x32_bf16(aqh[kc], bkh, s4[j], 0, 0, 0);
                s4[j] = __builtin_amdgcn_mfma_f32_16x16x32_bf16(aql[kc], bkh, s4[j], 0, 0, 0);
                s4[j] = __builtin_amdgcn_mfma_f32_16x16x32_bf16(aqh[kc], bkl, s4[j], 0, 0, 0);
            }
#pragma unroll
        for (int j = 0; j < 4; j++) s4[j] = s4[j] * 8.f;

#pragma unroll
        for (int r = 0; r < 4; r++) {
            float mx = fmaxf(fmaxf(s4[0][r], s4[1][r]), fmaxf(s4[2][r], s4[3][r]));
#pragma unroll
            for (int off = 1; off < 16; off <<= 1) mx = fmaxf(mx, __shfl_xor(mx, off, 64));
            float mn = fmaxf(m_r[r], mx);
            float corr = __expf(m_r[r] - mn);
            m_r[r] = mn;
            float rs = 0.f;
#pragma unroll
            for (int j = 0; j < 4; j++) {
                float p = __expf(s4[j][r] - mn);
                s4[j][r] = p; rs += p;
            }
#pragma unroll
            for (int off = 1; off < 16; off <<= 1) rs += __shfl_xor(rs, off, 64);
            l_r[r] = l_r[r] * corr + rs;
#pragma unroll
            for (int d0 = 0; d0 < 4; d0++) acc_o[d0][r] = acc_o[d0][r] * corr;
        }
#pragma unroll
        for (int j = 0; j < 4; j++)
#pragma unroll
            for (int r = 0; r < 4; r++) {
                int row = lb * 4 + r;
                int sg = (2 * j + (la >> 3)) ^ (row & 7);
                Ps[wid][row * 64 + sg * 8 + (la & 7)] = f2bf(s4[j][r]);
            }
        short8 pa[2];
#pragma unroll
        for (int kc = 0; kc < 2; kc++)
            pa[kc] = *(const short8*)(&Ps[wid][la * 64 + (((kc * 4 + lb) ^ (la & 7)) * 8)]);
#pragma unroll
        for (int d0 = 0; d0 < 4; d0++)
#pragma unroll
            for (int kc = 0; kc < 2; kc++) {
                short8 bv = *(const short8*)(&Vs[(d0 * 16 + la) * 64 + (((kc * 4 + lb) ^ (la & 7)) * 8)]);
                acc_o[d0] = __builtin_amdgcn_mfma_f32_16x16x32_bf16(pa[kc], bv, acc_o[d0], 0, 0, 0);
            }
        __syncthreads();
    }
#pragma unroll
    for (int r = 0; r < 4; r++) {
        float invl = 1.f / l_r[r];
        int tok = b * SS + q0 + wid * 16 + lb * 4 + r;
#pragma unroll
        for (int d0 = 0; d0 < 4; d0++)
            o[(size_t)tok * CC + h * HD + d0 * 16 + la] = f2bf(acc_o[d0][r] * invl);
    }
}

// ---------------- balance loss ----------------
__global__ __launch_bounds__(256) void loss_kernel(const float* __restrict__ et,
    const float* __restrict__ stats, float* __restrict__ out_loss)
{
    __shared__ float red[256];
    int tid = threadIdx.x;
    float s = 0.f;
    for (int i = tid; i < EE * CC; i += 256) { float v = et[i]; s += v * v; }
    red[tid] = s; __syncthreads();
    for (int off = 128; off > 0; off >>= 1) { if (tid < off) red[tid] += red[tid + off]; __syncthreads(); }
    if (tid == 0) {
        float bl = 0.f;
        for (int e = 0; e < EE; e++) {
            float f = stats[EE + e] / (float)(NT * KK);
            float P = stats[e] / (float)NT;
            bl += f * P;
        }
        *out_loss = (float)EE * bl + 0.01f * sqrtf(red[0]);
    }
}

extern "C" void kernel_launch(void* const* d_in, const int* in_sizes, int n_in,
                              void* d_out, int out_size, void* d_ws, size_t ws_size,
                              hipStream_t stream) {
    const float* x      = (const float*)d_in[0];
    const float* et     = (const float*)d_in[1];
    const float* ln1_g  = (const float*)d_in[2];
    const float* ln1_b  = (const float*)d_in[3];
    const float* qkv_w  = (const float*)d_in[4];
    const float* qkv_b  = (const float*)d_in[5];
    const float* proj_w = (const float*)d_in[6];
    const float* proj_b = (const float*)d_in[7];
    const float* ln2_g  = (const float*)d_in[8];
    const float* ln2_b  = (const float*)d_in[9];
    const float* fc1_w  = (const float*)d_in[10];
    const float* fc1_b  = (const float*)d_in[11];
    const float* fc2_w  = (const float*)d_in[12];
    const float* fc2_b  = (const float*)d_in[13];
    float* outp = (float*)d_out;
    char* base = (char*)d_ws;

    const size_t FIXED = 12714496;
    int EB = 1;
    if (ws_size >= FIXED + 8 * SLOTB) EB = 8;
    else if (ws_size >= FIXED + 4 * SLOTB) EB = 4;
    else if (ws_size >= FIXED + 2 * SLOTB) EB = 2;

    float* W      = (float*)(base);
    float* stats  = (float*)(base + 131072);
    u16*   xh_hi  = (u16*)  (base + 131584);
    u16*   xh_lo  = (u16*)  (base + 6423040);
    char* slot0 = base + FIXED;
    u16*   qkvTh  = (u16*)  (slot0);
    u16*   qkvTl  = (u16*)  (slot0 + 3538944);
    u16*   projT  = (u16*)  (slot0 + 7077888);
    u16*   fc1T   = (u16*)  (slot0 + 8257536);
    u16*   fc2T   = (u16*)  (slot0 + 12976128);
    float* biasq  = (float*)(slot0 + 17694720);
    float* biasf1 = (float*)(slot0 + 17711104);
    u16*   qk_hi  = (u16*)  (slot0 + 17727488);
    u16*   qk_lo  = (u16*)  (slot0 + 30310400);
    u16*   mlp1   = (u16*)  (slot0 + 17727488);   // aliases qk_hi+qk_lo (dead after attn)
    u16*   vtb    = (u16*)  (slot0 + 42893312);
    u16*   xmhat  = (u16*)  (slot0 + 42893312);   // aliases vt (dead after attn)
    u16*   obf    = (u16*)  (slot0 + 49184768);
    u16*   vraw   = obf;                          // aliases obf (dead before attn writes it)
    float* xmid   = (float*)(slot0 + 55476224);

    hipMemsetAsync(stats, 0, 16 * sizeof(float), stream);
    hipMemsetAsync(outp, 0, (size_t)NOUT * sizeof(float), stream);

    router_kernel<<<NT / 8, 256, 0, stream>>>(x, et, W, stats);
    ln_kernel<1><<<dim3(NT, 1), 256, 0, stream>>>(x, 0, xh_hi, xh_lo, 0);

    for (int ebase = 0; ebase < EE; ebase += EB) {
        prep_expert<<<dim3(7080, EB), 256, 0, stream>>>(
            qkv_w, qkv_b, proj_w, fc1_w, fc1_b, fc2_w,
            ln1_g, ln1_b, ln2_g, ln2_b,
            qkvTh, qkvTl, projT, fc1T, fc2T, biasq, biasf1, ebase);

        gemm_qk_dp<<<dim3(12 * 32, EB), 256, 0, stream>>>(
            xh_hi, xh_lo, qkvTh, qkvTl, biasq, qk_hi, qk_lo);

        gemm_v_dp<<<dim3(6 * 32, EB), 256, 0, stream>>>(xh_hi, qkvTh, biasq, vraw);

        vtrans<<<dim3(SS / 64, HH, BB * EB), 256, 0, stream>>>(vraw, vtb);

        attn_mfma<<<dim3(SS / 64, HH, BB * EB), 256, 0, stream>>>(qk_hi, qk_lo, vtb, obf);

        gemm_proj_dp<<<dim3(6 * 32, EB), 256, 0, stream>>>(
            obf, projT, proj_b + (size_t)ebase * CC, x, xmid);

        ln_kernel<0><<<dim3(NT, EB), 256, 0, stream>>>(xmid, SLOT_F32, xmhat, nullptr, SLOT_U16);

        gemm_fc1_dp<<<dim3(24 * 32, EB), 256, 0, stream>>>(xmhat, fc1T, biasf1, mlp1);

        gemm_fc2_dp<<<dim3(6 * 32, EB), 256, 0, stream>>>(
            mlp1, fc2T, fc2_b + (size_t)ebase * CC, xmid, W, ebase, x, outp);
    }

    loss_kernel<<<1, 256, 0, stream>>>(et, stats, outp + NOUT);
}

// Round 20
// 1420.192 us; speedup vs baseline: 1.1255x; 1.1230x over previous
//
#include <hip/hip_runtime.h>
#include <hip/hip_bf16.h>

#define BB 8
#define SS 512
#define CC 768
#define HH 12
#define HD 64
#define EE 8
#define KK 2
#define MLPH 3072
#define NT (BB*SS)
#define NOUT (NT*CC)

#define SLOTB      68059136ull
#define SLOT_U16   34029568ull
#define SLOT_F32   17014784ull

typedef unsigned int u32;
typedef unsigned short u16;
typedef __attribute__((ext_vector_type(8))) short short8;
typedef __attribute__((ext_vector_type(4))) float f32x4;

__device__ __forceinline__ u16 f2bf(float f) {
    u32 u = __builtin_bit_cast(u32, f);
    u32 r = (u + 0x7fffu + ((u >> 16) & 1u)) >> 16;
    return (u16)r;
}
__device__ __forceinline__ float bf2f(u16 h) {
    u32 u = ((u32)h) << 16;
    return __builtin_bit_cast(float, u);
}
__device__ __forceinline__ void gl_lds16(const void* g, void* l) {
    __builtin_amdgcn_global_load_lds(
        (const __attribute__((address_space(1))) u32*)g,
        (__attribute__((address_space(3))) u32*)l, 16, 0, 0);
}
// XCD-band mapping: each XCD owns 4 consecutive row-blocks; col-major in band.
__device__ __forceinline__ void swz_rc(int bid, int& bm, int& bn) {
    int xcd = bid & 7, off = bid >> 3;
    bm = (xcd * 4 + (off & 3)) * 128;
    bn = (off >> 2) * 128;
}

// stage a 128x64 bf16 tile with 16B-chunk XOR swizzle on the SOURCE (m173), 256 threads
__device__ __forceinline__ void stage128x64(const u16* __restrict__ G, size_t ldg,
                                            u16* s, int tid)
{
    int wid = tid >> 6, lane = tid & 63;
#pragma unroll
    for (int it = 0; it < 4; ++it) {
        int cb = it * 256 + wid * 64;
        int c = cb + lane;
        int row = c >> 3;
        int ch = (c & 7) ^ (row & 7);
        gl_lds16(G + (size_t)row * ldg + ch * 8, s + cb * 8);
    }
}
__device__ __forceinline__ short8 frag64(const u16* s, int row, int kc, int lb) {
    int ch = (kc * 4 + lb) ^ (row & 7);
    return *(const short8*)(s + row * 64 + ch * 8);
}

// deep-pipe staging: one 128x32 A-tile + one 128x32 B-tile; 4 vmem instr per wave
__device__ __forceinline__ void stg_dp(const u16* __restrict__ A, const u16* __restrict__ B,
                                       int ldk, u16* sA, u16* sB, int t, int tid)
{
    int wid = tid >> 6, lane = tid & 63;
#pragma unroll
    for (int rd = 0; rd < 2; rd++) {
        int cb = rd * 256 + wid * 64;
        int c = cb + lane;
        gl_lds16(A + (size_t)(c >> 2) * ldk + t * 32 + (c & 3) * 8, sA + cb * 8);
    }
#pragma unroll
    for (int rd = 0; rd < 2; rd++) {
        int cb = rd * 256 + wid * 64;
        int c = cb + lane;
        gl_lds16(B + (size_t)(c >> 2) * ldk + t * 32 + (c & 3) * 8, sB + cb * 8);
    }
}

// ---------------- Router ----------------
__global__ __launch_bounds__(256) void router_kernel(const float* __restrict__ x,
    const float* __restrict__ et, float* __restrict__ W, float* __restrict__ stats)
{
    __shared__ float etl[EE * CC];
    __shared__ float pred[4][2 * EE];
    int tid = threadIdx.x;
    for (int i = tid; i < EE * CC; i += 256) etl[i] = et[i];
    __syncthreads();
    int wid = tid >> 6, lane = tid & 63;
    float psum[EE] = {}, csum[EE] = {};
    for (int i = 0; i < 2; i++) {
        int t = blockIdx.x * 8 + wid * 2 + i;
        const float* xr = x + (size_t)t * CC;
        float acc[EE] = {};
        for (int c = lane; c < CC; c += 64) {
            float xv = xr[c];
#pragma unroll
            for (int e = 0; e < EE; e++) acc[e] += xv * etl[e * CC + c];
        }
#pragma unroll
        for (int e = 0; e < EE; e++)
            for (int off = 1; off < 64; off <<= 1) acc[e] += __shfl_xor(acc[e], off, 64);
        if (lane == 0) {
            const float inv = 0.03608439182435161f;
            float l[EE], m = -1e30f;
#pragma unroll
            for (int e = 0; e < EE; e++) { l[e] = acc[e] * inv; m = fmaxf(m, l[e]); }
            float p[EE], sum = 0.f;
#pragma unroll
            for (int e = 0; e < EE; e++) { p[e] = __expf(l[e] - m); sum += p[e]; }
            int i1 = 0;
#pragma unroll
            for (int e = 1; e < EE; e++) if (p[e] > p[i1]) i1 = e;
            int i2 = -1;
#pragma unroll
            for (int e = 0; e < EE; e++) if (e != i1 && (i2 < 0 || p[e] > p[i2])) i2 = e;
            float wn = p[i1] + p[i2];
#pragma unroll
            for (int e = 0; e < EE; e++) W[t * EE + e] = 0.f;
            W[t * EE + i1] = p[i1] / wn;
            W[t * EE + i2] = p[i2] / wn;
#pragma unroll
            for (int e = 0; e < EE; e++) psum[e] += p[e] / sum;
            csum[i1] += 1.f; csum[i2] += 1.f;
        }
    }
    if (lane == 0) {
#pragma unroll
        for (int e = 0; e < EE; e++) { pred[wid][e] = psum[e]; pred[wid][EE + e] = csum[e]; }
    }
    __syncthreads();
    if (tid < 2 * EE) {
        float s = pred[0][tid] + pred[1][tid] + pred[2][tid] + pred[3][tid];
        atomicAdd(&stats[tid], s);
    }
}

// ---------------- plain LayerNorm (affine folded), batched over y ----------------
template<int MODE>
__global__ __launch_bounds__(256) void ln_kernel(const float* __restrict__ x, size_t xslot,
    u16* __restrict__ out_hi, u16* __restrict__ out_lo, size_t oslot)
{
    int t = blockIdx.x;
    int eb = blockIdx.y;
    const float* xr = x + (size_t)eb * xslot + (size_t)t * CC;
    __shared__ float red[256];
    int tid = threadIdx.x;
    float v[3];
    float s = 0.f;
#pragma unroll
    for (int i = 0; i < 3; i++) { v[i] = xr[tid + i * 256]; s += v[i]; }
    red[tid] = s; __syncthreads();
    for (int off = 128; off > 0; off >>= 1) { if (tid < off) red[tid] += red[tid + off]; __syncthreads(); }
    float mu = red[0] / (float)CC;
    __syncthreads();
    float s2 = 0.f;
#pragma unroll
    for (int i = 0; i < 3; i++) { float d = v[i] - mu; s2 += d * d; }
    red[tid] = s2; __syncthreads();
    for (int off = 128; off > 0; off >>= 1) { if (tid < off) red[tid] += red[tid + off]; __syncthreads(); }
    float var = red[0] / (float)CC;
    float sc = rsqrtf(var + 1e-5f);
#pragma unroll
    for (int i = 0; i < 3; i++) {
        int c = tid + i * 256;
        float val = (v[i] - mu) * sc;
        u16 hi = f2bf(val);
        out_hi[(size_t)eb * oslot + (size_t)t * CC + c] = hi;
        if (MODE) out_lo[(size_t)eb * oslot + (size_t)t * CC + c] = f2bf(val - bf2f(hi));
    }
}

// ---------------- per-expert weight prep, batched over y ----------------
__global__ __launch_bounds__(256) void prep_expert(
    const float* __restrict__ qkv_w0, const float* __restrict__ qkv_b0,
    const float* __restrict__ proj_w0,
    const float* __restrict__ fc1_w0, const float* __restrict__ fc1_b0,
    const float* __restrict__ fc2_w0,
    const float* __restrict__ g1_0, const float* __restrict__ b1_0,
    const float* __restrict__ g2_0, const float* __restrict__ b2_0,
    u16* __restrict__ qkvTh, u16* __restrict__ qkvTl,
    u16* __restrict__ projT, u16* __restrict__ fc1T, u16* __restrict__ fc2T,
    float* __restrict__ biasq, float* __restrict__ biasf1, int ebase)
{
    __shared__ float tile[32][33];
    __shared__ float bsh[CC];
    __shared__ float redg[256];
    int bid = blockIdx.x;
    int eb = blockIdx.y;
    int ge = ebase + eb;
    int tid = threadIdx.x;
    const float* qkv_w = qkv_w0 + (size_t)ge * CC * 3 * CC;
    const float* qkv_b = qkv_b0 + (size_t)ge * 3 * CC;
    const float* proj_w = proj_w0 + (size_t)ge * CC * CC;
    const float* fc1_w = fc1_w0 + (size_t)ge * CC * MLPH;
    const float* fc1_b = fc1_b0 + (size_t)ge * MLPH;
    const float* fc2_w = fc2_w0 + (size_t)ge * MLPH * CC;
    const float* g1 = g1_0 + (size_t)ge * CC;
    const float* b1 = b1_0 + (size_t)ge * CC;
    const float* g2 = g2_0 + (size_t)ge * CC;
    const float* b2 = b2_0 + (size_t)ge * CC;

    if (bid < 6912) {
        const float* src; const float* scale = nullptr;
        u16 *dh, *dl = nullptr; int N, Kd, n0, k0;
        if (bid < 1728) {
            src = qkv_w; scale = g1;
            dh = qkvTh + (size_t)eb * SLOT_U16; dl = qkvTl + (size_t)eb * SLOT_U16;
            N = 2304; Kd = 768; n0 = (bid % 72) * 32; k0 = (bid / 72) * 32;
        } else if (bid < 2304) {
            int i = bid - 1728;
            src = proj_w; dh = projT + (size_t)eb * SLOT_U16; N = 768; Kd = 768;
            n0 = (i % 24) * 32; k0 = (i / 24) * 32;
        } else if (bid < 4608) {
            int i = bid - 2304;
            src = fc1_w; scale = g2; dh = fc1T + (size_t)eb * SLOT_U16; N = 3072; Kd = 768;
            n0 = (i % 96) * 32; k0 = (i / 96) * 32;
        } else {
            int i = bid - 4608;
            src = fc2_w; dh = fc2T + (size_t)eb * SLOT_U16; N = 768; Kd = 3072;
            n0 = (i % 24) * 32; k0 = (i / 24) * 32;
        }
        int tx = tid & 31, ty = tid >> 5;
#pragma unroll
        for (int i = 0; i < 32; i += 8) {
            float v = src[(size_t)(k0 + ty + i) * N + n0 + tx];
            if (scale) v *= scale[k0 + ty + i];
            tile[ty + i][tx] = v;
        }
        __syncthreads();
#pragma unroll
        for (int i = 0; i < 32; i += 8) {
            float v = tile[tx][ty + i];
            u16 hi = f2bf(v);
            dh[(size_t)(n0 + ty + i) * Kd + k0 + tx] = hi;
            if (dl) dl[(size_t)(n0 + ty + i) * Kd + k0 + tx] = f2bf(v - bf2f(hi));
        }
    } else {
        const float* bv; const float* wsrc; const float* badd;
        float* dst; int N, n0;
        if (bid < 6984) { bv = b1; wsrc = qkv_w; badd = qkv_b; dst = biasq + (size_t)eb * SLOT_F32; N = 2304; n0 = (bid - 6912) * 32; }
        else            { bv = b2; wsrc = fc1_w; badd = fc1_b; dst = biasf1 + (size_t)eb * SLOT_F32; N = MLPH; n0 = (bid - 6984) * 32; }
        for (int i = tid; i < CC; i += 256) bsh[i] = bv[i];
        __syncthreads();
        int g = tid & 31, l8 = tid >> 5;
        int n = n0 + g;
        float acc = 0.f;
        for (int k = l8; k < CC; k += 8) acc += bsh[k] * wsrc[(size_t)k * N + n];
        redg[tid] = acc; __syncthreads();
        if (tid < 32) {
            float sum = 0.f;
#pragma unroll
            for (int i = 0; i < 8; i++) sum += redg[tid + i * 32];
            dst[n0 + tid] = sum + badd[n0 + tid];
        }
    }
}

// ---------------- qkv GEMM, BK=64: split-precision q,k cols; plain v cols (coalesced V write) ----------------
__global__ __launch_bounds__(256) void gemm_qkv_bk64(
    const u16* __restrict__ Ah, const u16* __restrict__ Al,
    const u16* __restrict__ Bh0, const u16* __restrict__ Bl0,
    const float* __restrict__ biasq0, u16* __restrict__ qk_hi0,
    u16* __restrict__ qk_lo0, u16* __restrict__ vraw0)
{
    __shared__ __align__(16) u16 sAh[128 * 64], sAl[128 * 64];
    __shared__ __align__(16) u16 sBh[128 * 64], sBl[128 * 64];
    int tid = threadIdx.x;
    int eb = blockIdx.y;
    int bm, bn;
    swz_rc(blockIdx.x, bm, bn);
    bool qk_tile = (bn < 1536);
    int wid = tid >> 6, lane = tid & 63;
    int wr = wid >> 1, wc = wid & 1;
    int la = lane & 15, lb = lane >> 4;
    const u16* Bh = Bh0 + (size_t)eb * SLOT_U16;
    const u16* Bl = Bl0 + (size_t)eb * SLOT_U16;
    const float* bias = biasq0 + (size_t)eb * SLOT_F32;
    u16* qk_hi = qk_hi0 + (size_t)eb * SLOT_U16;
    u16* qk_lo = qk_lo0 + (size_t)eb * SLOT_U16;
    u16* vraw = vraw0 + (size_t)eb * SLOT_U16;

    f32x4 acc[4][4];
#pragma unroll
    for (int i = 0; i < 4; i++)
#pragma unroll
        for (int j = 0; j < 4; j++) acc[i][j] = (f32x4){0.f, 0.f, 0.f, 0.f};

    const u16* Abh = Ah + (size_t)bm * CC;
    const u16* Abl = Al + (size_t)bm * CC;
    const u16* Bbh = Bh + (size_t)bn * CC;
    const u16* Bbl = Bl + (size_t)bn * CC;
    for (int k0 = 0; k0 < CC; k0 += 64) {
        stage128x64(Abh + k0, CC, sAh, tid);
        stage128x64(Bbh + k0, CC, sBh, tid);
        if (qk_tile) {
            stage128x64(Abl + k0, CC, sAl, tid);
            stage128x64(Bbl + k0, CC, sBl, tid);
        }
        __syncthreads();
        if (qk_tile) {
#pragma unroll
            for (int kc = 0; kc < 2; kc++) {
                short8 avh[4], avl[4], bvh[4], bvl[4];
#pragma unroll
                for (int i = 0; i < 4; i++) {
                    int row = wr * 64 + i * 16 + la;
                    avh[i] = frag64(sAh, row, kc, lb);
                    avl[i] = frag64(sAl, row, kc, lb);
                }
#pragma unroll
                for (int j = 0; j < 4; j++) {
                    int row = wc * 64 + j * 16 + la;
                    bvh[j] = frag64(sBh, row, kc, lb);
                    bvl[j] = frag64(sBl, row, kc, lb);
                }
#pragma unroll
                for (int i = 0; i < 4; i++)
#pragma unroll
                    for (int j = 0; j < 4; j++) {
                        acc[i][j] = __builtin_amdgcn_mfma_f32_16x16x32_bf16(avh[i], bvh[j], acc[i][j], 0, 0, 0);
                        acc[i][j] = __builtin_amdgcn_mfma_f32_16x16x32_bf16(avh[i], bvl[j], acc[i][j], 0, 0, 0);
                        acc[i][j] = __builtin_amdgcn_mfma_f32_16x16x32_bf16(avl[i], bvh[j], acc[i][j], 0, 0, 0);
                    }
            }
        } else {
#pragma unroll
            for (int kc = 0; kc < 2; kc++) {
                short8 avh[4], bvh[4];
#pragma unroll
                for (int i = 0; i < 4; i++) avh[i] = frag64(sAh, wr * 64 + i * 16 + la, kc, lb);
#pragma unroll
                for (int j = 0; j < 4; j++) bvh[j] = frag64(sBh, wc * 64 + j * 16 + la, kc, lb);
#pragma unroll
                for (int i = 0; i < 4; i++)
#pragma unroll
                    for (int j = 0; j < 4; j++)
                        acc[i][j] = __builtin_amdgcn_mfma_f32_16x16x32_bf16(avh[i], bvh[j], acc[i][j], 0, 0, 0);
            }
        }
        __syncthreads();
    }
#pragma unroll
    for (int i = 0; i < 4; i++) {
#pragma unroll
        for (int j = 0; j < 4; j++) {
            int gn = bn + wc * 64 + j * 16 + la;
            float bsv = bias[gn];
#pragma unroll
            for (int r = 0; r < 4; r++) {
                int gm = bm + wr * 64 + i * 16 + lb * 4 + r;
                float v = acc[i][j][r] + bsv;
                if (gn < 1536) {
                    u16 hi = f2bf(v);
                    qk_hi[(size_t)gm * 1536 + gn] = hi;
                    qk_lo[(size_t)gm * 1536 + gn] = f2bf(v - bf2f(hi));
                } else {
                    vraw[(size_t)gm * CC + (gn - 1536)] = f2bf(v);   // coalesced
                }
            }
        }
    }
}

// ---------------- V transpose: vraw [4096][768] -> vt [b*H+h][d][s] ----------------
__global__ __launch_bounds__(256) void vtrans(const u16* __restrict__ vraw0,
    u16* __restrict__ vt0)
{
    __shared__ u16 tile[64][65];
    int st = blockIdx.x;                 // s-tile 0..7
    int h = blockIdx.y;
    int z = blockIdx.z;
    int b = z & (BB - 1), eb = z >> 3;
    const u16* vraw = vraw0 + (size_t)eb * SLOT_U16;
    u16* vt = vt0 + (size_t)eb * SLOT_U16;
    int tid = threadIdx.x;
    int row = tid >> 3, ch = tid & 7;
#pragma unroll
    for (int it = 0; it < 2; it++) {
        int s = it * 32 + row;
        const u16* src = vraw + (size_t)(b * SS + st * 64 + s) * CC + h * HD + ch * 8;
        short8 v = *(const short8*)src;
#pragma unroll
        for (int k = 0; k < 8; k++) tile[s][ch * 8 + k] = (u16)v[k];
    }
    __syncthreads();
#pragma unroll
    for (int it = 0; it < 2; it++) {
        int d = it * 32 + row;
        u16* dst = vt + ((size_t)((b * HH + h) * HD + d)) * SS + st * 64 + ch * 8;
        short8 v;
#pragma unroll
        for (int k = 0; k < 8; k++) v[k] = (short)tile[ch * 8 + k][d];
        *(short8*)dst = v;
    }
}

// ---------------- deep-pipe GEMM body: 128x128, BK=32, 3-buf, counted vmcnt ----------------
template<int EPI>
__device__ __forceinline__ void gemm_dp_body(
    const u16* __restrict__ Ab, const u16* __restrict__ Bb, int Kdim,
    const float* __restrict__ biasp, const float* __restrict__ resp,
    const float* __restrict__ Wt, int ge, const float* __restrict__ xinit,
    void* __restrict__ Cout, int N, int bm, int bn)
{
    __shared__ __align__(16) u16 sA[3][128 * 32];
    __shared__ __align__(16) u16 sB[3][128 * 32];
    int tid = threadIdx.x;
    int wid = tid >> 6, lane = tid & 63;
    int wr = wid >> 1, wc = wid & 1;
    int la = lane & 15, lb = lane >> 4;
    int NTILE = Kdim / 32;

    f32x4 acc[4][4];
#pragma unroll
    for (int i = 0; i < 4; i++)
#pragma unroll
        for (int j = 0; j < 4; j++) acc[i][j] = (f32x4){0.f, 0.f, 0.f, 0.f};

    stg_dp(Ab, Bb, Kdim, sA[0], sB[0], 0, tid);
    stg_dp(Ab, Bb, Kdim, sA[1], sB[1], 1, tid);

    for (int t = 0; t < NTILE; t++) {
        if (t < NTILE - 1) asm volatile("s_waitcnt vmcnt(4)" ::: "memory");
        else               asm volatile("s_waitcnt vmcnt(0)" ::: "memory");
        __builtin_amdgcn_s_barrier();
        asm volatile("" ::: "memory");

        const u16* cA = &sA[t % 3][0];
        const u16* cB = &sB[t % 3][0];
        __builtin_amdgcn_s_setprio(1);
        short8 bv[4];
#pragma unroll
        for (int j = 0; j < 4; j++)
            bv[j] = *(const short8*)(cB + ((size_t)(wc * 64 + j * 16 + la) * 4 + lb) * 8);
#pragma unroll
        for (int i = 0; i < 4; i++) {
            short8 av = *(const short8*)(cA + ((size_t)(wr * 64 + i * 16 + la) * 4 + lb) * 8);
#pragma unroll
            for (int j = 0; j < 4; j++)
                acc[i][j] = __builtin_amdgcn_mfma_f32_16x16x32_bf16(av, bv[j], acc[i][j], 0, 0, 0);
        }
        __builtin_amdgcn_s_setprio(0);

        if (t + 2 < NTILE) stg_dp(Ab, Bb, Kdim, sA[(t + 2) % 3], sB[(t + 2) % 3], t + 2, tid);
    }

#pragma unroll
    for (int i = 0; i < 4; i++) {
#pragma unroll
        for (int j = 0; j < 4; j++) {
            int gn = bn + wc * 64 + j * 16 + la;
            float bsv = biasp[gn];
#pragma unroll
            for (int r = 0; r < 4; r++) {
                int gm = bm + wr * 64 + i * 16 + lb * 4 + r;
                size_t idx = (size_t)gm * N + gn;
                float v = acc[i][j][r] + bsv;
                if (EPI == 1) {
                    ((float*)Cout)[idx] = resp[idx] + v;
                } else if (EPI == 2) {
                    float gel = 0.5f * v * (1.0f + erff(v * 0.70710678118654752f));
                    ((u16*)Cout)[idx] = f2bf(gel);
                } else {
                    float w = Wt[(size_t)gm * EE + ge];
                    float val = w * (v + resp[idx]);
                    if (ge == 0) val += xinit[idx];
                    atomicAdd(&((float*)Cout)[idx], val);
                }
            }
        }
    }
}

// proj: A=obf [4096][768], B=projT [768][768] -> xmid f32; grid (192, EB)
__global__ __launch_bounds__(256) void gemm_proj_dp(
    const u16* __restrict__ A0, const u16* __restrict__ BT0,
    const float* __restrict__ bias0, const float* __restrict__ x,
    float* __restrict__ C0)
{
    int eb = blockIdx.y;
    int bm, bn;
    swz_rc(blockIdx.x, bm, bn);
    gemm_dp_body<1>(A0 + (size_t)eb * SLOT_U16 + (size_t)bm * CC,
                    BT0 + (size_t)eb * SLOT_U16 + (size_t)bn * CC, CC,
                    bias0 + (size_t)eb * CC, x, nullptr, 0, nullptr,
                    C0 + (size_t)eb * SLOT_F32, CC, bm, bn);
}

// fc1: grid (768, EB)
__global__ __launch_bounds__(256) void gemm_fc1_dp(
    const u16* __restrict__ A0, const u16* __restrict__ BT0,
    const float* __restrict__ bias0, u16* __restrict__ C0)
{
    int eb = blockIdx.y;
    int bm, bn;
    swz_rc(blockIdx.x, bm, bn);
    gemm_dp_body<2>(A0 + (size_t)eb * SLOT_U16 + (size_t)bm * CC,
                    BT0 + (size_t)eb * SLOT_U16 + (size_t)bn * CC, CC,
                    bias0 + (size_t)eb * SLOT_F32, nullptr, nullptr, 0, nullptr,
                    C0 + (size_t)eb * SLOT_U16, MLPH, bm, bn);
}

// fc2: grid (192, EB)
__global__ __launch_bounds__(256) void gemm_fc2_dp(
    const u16* __restrict__ A0, const u16* __restrict__ BT0,
    const float* __restrict__ bias0, const float* __restrict__ res0,
    const float* __restrict__ Wt, int ebase, const float* __restrict__ xinit,
    float* __restrict__ Cout)
{
    int eb = blockIdx.y;
    int bm, bn;
    swz_rc(blockIdx.x, bm, bn);
    gemm_dp_body<5>(A0 + (size_t)eb * SLOT_U16 + (size_t)bm * MLPH,
                    BT0 + (size_t)eb * SLOT_U16 + (size_t)bn * MLPH, MLPH,
                    bias0 + (size_t)eb * CC, res0 + (size_t)eb * SLOT_F32,
                    Wt, ebase + eb, xinit, Cout, CC, bm, bn);
}

// ---------------- MFMA flash attention, split QK^T, single-buffer, batched ----------------
__global__ __launch_bounds__(256) void attn_mfma(const u16* __restrict__ qk_hi0,
    const u16* __restrict__ qk_lo0, const u16* __restrict__ vt0, u16* __restrict__ o0)
{
    int q0 = blockIdx.x * 64;
    int h = blockIdx.y;
    int z = blockIdx.z;
    int b = z & (BB - 1), eb = z >> 3;
    int tid = threadIdx.x, wid = tid >> 6, lane = tid & 63;
    int la = lane & 15, lb = lane >> 4;
    __shared__ __align__(16) u16 Ksh[64 * 64];
    __shared__ __align__(16) u16 Ksl[64 * 64];
    __shared__ __align__(16) u16 Vs[64 * 64];
    __shared__ __align__(16) u16 Ps[4][16 * 64];

    const u16* qk_hi = qk_hi0 + (size_t)eb * SLOT_U16;
    const u16* qk_lo = qk_lo0 + (size_t)eb * SLOT_U16;
    const u16* vt = vt0 + (size_t)eb * SLOT_U16;
    u16* o = o0 + (size_t)eb * SLOT_U16;

    short8 aqh[2], aql[2];
    {
        size_t qoff = (size_t)(b * SS + q0 + wid * 16 + la) * 1536 + h * HD;
#pragma unroll
        for (int kc = 0; kc < 2; kc++) {
            aqh[kc] = *(const short8*)(qk_hi + qoff + kc * 32 + lb * 8);
            aql[kc] = *(const short8*)(qk_lo + qoff + kc * 32 + lb * 8);
        }
    }
    const u16* kbh = qk_hi + (size_t)(b * SS) * 1536 + CC + h * HD;
    const u16* kbl = qk_lo + (size_t)(b * SS) * 1536 + CC + h * HD;
    const u16* vtbase = vt + (size_t)((b * HH + h) * HD) * SS;

    float m_r[4], l_r[4];
    f32x4 acc_o[4];
#pragma unroll
    for (int r = 0; r < 4; r++) { m_r[r] = -1e30f; l_r[r] = 0.f; }
#pragma unroll
    for (int d0 = 0; d0 < 4; d0++) acc_o[d0] = (f32x4){0.f, 0.f, 0.f, 0.f};

    for (int kt = 0; kt < SS; kt += 64) {
#pragma unroll
        for (int it = 0; it < 2; it++) {
            int base = it * 256 + wid * 64;
            int c = base + lane;
            int row = c >> 3;
            int gk = (c & 7) ^ (row & 7);
            gl_lds16(kbh + (size_t)(kt + row) * 1536 + gk * 8, Ksh + base * 8);
            gl_lds16(kbl + (size_t)(kt + row) * 1536 + gk * 8, Ksl + base * 8);
            gl_lds16(vtbase + (size_t)row * SS + kt + gk * 8, Vs + base * 8);
        }
        __syncthreads();

        f32x4 s4[4];
#pragma unroll
        for (int j = 0; j < 4; j++) s4[j] = (f32x4){0.f, 0.f, 0.f, 0.f};
#pragma unroll
        for (int kc = 0; kc < 2; kc++)
#pragma unroll
            for (int j = 0; j < 4; j++) {
                size_t off = (size_t)(j * 16 + la) * 64 + (((kc * 4 + lb) ^ (la & 7)) * 8);
                short8 bkh = *(const short8*)(Ksh + off);
                short8 bkl = *(const short8*)(Ksl + off);
                s4[j] = __builtin_amdgcn_mfma_f32_16x16x32_bf16(aqh[kc], bkh, s4[j], 0, 0, 0);
                s4[j] = __builtin_amdgcn_mfma_f32_16x16x32_bf16(aql[kc], bkh, s4[j], 0, 0, 0);
                s4[j] = __builtin_amdgcn_mfma_f32_16x16x32_bf16(aqh[kc], bkl, s4[j], 0, 0, 0);
            }
#pragma unroll
        for (int j = 0; j < 4; j++) s4[j] = s4[j] * 8.f;

#pragma unroll
        for (int r = 0; r < 4; r++) {
            float mx = fmaxf(fmaxf(s4[0][r], s4[1][r]), fmaxf(s4[2][r], s4[3][r]));
#pragma unroll
            for (int off = 1; off < 16; off <<= 1) mx = fmaxf(mx, __shfl_xor(mx, off, 64));
            float mn = fmaxf(m_r[r], mx);
            float corr = __expf(m_r[r] - mn);
            m_r[r] = mn;
            float rs = 0.f;
#pragma unroll
            for (int j = 0; j < 4; j++) {
                float p = __expf(s4[j][r] - mn);
                s4[j][r] = p; rs += p;
            }
#pragma unroll
            for (int off = 1; off < 16; off <<= 1) rs += __shfl_xor(rs, off, 64);
            l_r[r] = l_r[r] * corr + rs;
#pragma unroll
            for (int d0 = 0; d0 < 4; d0++) acc_o[d0][r] = acc_o[d0][r] * corr;
        }
#pragma unroll
        for (int j = 0; j < 4; j++)
#pragma unroll
            for (int r = 0; r < 4; r++) {
                int row = lb * 4 + r;
                int sg = (2 * j + (la >> 3)) ^ (row & 7);
                Ps[wid][row * 64 + sg * 8 + (la & 7)] = f2bf(s4[j][r]);
            }
        short8 pa[2];
#pragma unroll
        for (int kc = 0; kc < 2; kc++)
            pa[kc] = *(const short8*)(&Ps[wid][la * 64 + (((kc * 4 + lb) ^ (la & 7)) * 8)]);
#pragma unroll
        for (int d0 = 0; d0 < 4; d0++)
#pragma unroll
            for (int kc = 0; kc < 2; kc++) {
                short8 bv = *(const short8*)(&Vs[(d0 * 16 + la) * 64 + (((kc * 4 + lb) ^ (la & 7)) * 8)]);
                acc_o[d0] = __builtin_amdgcn_mfma_f32_16x16x32_bf16(pa[kc], bv, acc_o[d0], 0, 0, 0);
            }
        __syncthreads();
    }
#pragma unroll
    for (int r = 0; r < 4; r++) {
        float invl = 1.f / l_r[r];
        int tok = b * SS + q0 + wid * 16 + lb * 4 + r;
#pragma unroll
        for (int d0 = 0; d0 < 4; d0++)
            o[(size_t)tok * CC + h * HD + d0 * 16 + la] = f2bf(acc_o[d0][r] * invl);
    }
}

// ---------------- balance loss ----------------
__global__ __launch_bounds__(256) void loss_kernel(const float* __restrict__ et,
    const float* __restrict__ stats, float* __restrict__ out_loss)
{
    __shared__ float red[256];
    int tid = threadIdx.x;
    float s = 0.f;
    for (int i = tid; i < EE * CC; i += 256) { float v = et[i]; s += v * v; }
    red[tid] = s; __syncthreads();
    for (int off = 128; off > 0; off >>= 1) { if (tid < off) red[tid] += red[tid + off]; __syncthreads(); }
    if (tid == 0) {
        float bl = 0.f;
        for (int e = 0; e < EE; e++) {
            float f = stats[EE + e] / (float)(NT * KK);
            float P = stats[e] / (float)NT;
            bl += f * P;
        }
        *out_loss = (float)EE * bl + 0.01f * sqrtf(red[0]);
    }
}

extern "C" void kernel_launch(void* const* d_in, const int* in_sizes, int n_in,
                              void* d_out, int out_size, void* d_ws, size_t ws_size,
                              hipStream_t stream) {
    const float* x      = (const float*)d_in[0];
    const float* et     = (const float*)d_in[1];
    const float* ln1_g  = (const float*)d_in[2];
    const float* ln1_b  = (const float*)d_in[3];
    const float* qkv_w  = (const float*)d_in[4];
    const float* qkv_b  = (const float*)d_in[5];
    const float* proj_w = (const float*)d_in[6];
    const float* proj_b = (const float*)d_in[7];
    const float* ln2_g  = (const float*)d_in[8];
    const float* ln2_b  = (const float*)d_in[9];
    const float* fc1_w  = (const float*)d_in[10];
    const float* fc1_b  = (const float*)d_in[11];
    const float* fc2_w  = (const float*)d_in[12];
    const float* fc2_b  = (const float*)d_in[13];
    float* outp = (float*)d_out;
    char* base = (char*)d_ws;

    const size_t FIXED = 12714496;
    int EB = 1;
    if (ws_size >= FIXED + 8 * SLOTB) EB = 8;
    else if (ws_size >= FIXED + 4 * SLOTB) EB = 4;
    else if (ws_size >= FIXED + 2 * SLOTB) EB = 2;

    float* W      = (float*)(base);
    float* stats  = (float*)(base + 131072);
    u16*   xh_hi  = (u16*)  (base + 131584);
    u16*   xh_lo  = (u16*)  (base + 6423040);
    char* slot0 = base + FIXED;
    u16*   qkvTh  = (u16*)  (slot0);
    u16*   qkvTl  = (u16*)  (slot0 + 3538944);
    u16*   projT  = (u16*)  (slot0 + 7077888);
    u16*   fc1T   = (u16*)  (slot0 + 8257536);
    u16*   fc2T   = (u16*)  (slot0 + 12976128);
    float* biasq  = (float*)(slot0 + 17694720);
    float* biasf1 = (float*)(slot0 + 17711104);
    u16*   qk_hi  = (u16*)  (slot0 + 17727488);
    u16*   qk_lo  = (u16*)  (slot0 + 30310400);
    u16*   mlp1   = (u16*)  (slot0 + 17727488);   // aliases qk_hi+qk_lo (dead after attn)
    u16*   vtb    = (u16*)  (slot0 + 42893312);
    u16*   xmhat  = (u16*)  (slot0 + 42893312);   // aliases vt (dead after attn)
    u16*   obf    = (u16*)  (slot0 + 49184768);
    u16*   vraw   = obf;                          // aliases obf (dead before attn writes it)
    float* xmid   = (float*)(slot0 + 55476224);

    hipMemsetAsync(stats, 0, 16 * sizeof(float), stream);
    hipMemsetAsync(outp, 0, (size_t)NOUT * sizeof(float), stream);

    router_kernel<<<NT / 8, 256, 0, stream>>>(x, et, W, stats);
    ln_kernel<1><<<dim3(NT, 1), 256, 0, stream>>>(x, 0, xh_hi, xh_lo, 0);

    for (int ebase = 0; ebase < EE; ebase += EB) {
        prep_expert<<<dim3(7080, EB), 256, 0, stream>>>(
            qkv_w, qkv_b, proj_w, fc1_w, fc1_b, fc2_w,
            ln1_g, ln1_b, ln2_g, ln2_b,
            qkvTh, qkvTl, projT, fc1T, fc2T, biasq, biasf1, ebase);

        gemm_qkv_bk64<<<dim3(18 * 32, EB), 256, 0, stream>>>(
            xh_hi, xh_lo, qkvTh, qkvTl, biasq, qk_hi, qk_lo, vraw);

        vtrans<<<dim3(SS / 64, HH, BB * EB), 256, 0, stream>>>(vraw, vtb);

        attn_mfma<<<dim3(SS / 64, HH, BB * EB), 256, 0, stream>>>(qk_hi, qk_lo, vtb, obf);

        gemm_proj_dp<<<dim3(6 * 32, EB), 256, 0, stream>>>(
            obf, projT, proj_b + (size_t)ebase * CC, x, xmid);

        ln_kernel<0><<<dim3(NT, EB), 256, 0, stream>>>(xmid, SLOT_F32, xmhat, nullptr, SLOT_U16);

        gemm_fc1_dp<<<dim3(24 * 32, EB), 256, 0, stream>>>(xmhat, fc1T, biasf1, mlp1);

        gemm_fc2_dp<<<dim3(6 * 32, EB), 256, 0, stream>>>(
            mlp1, fc2T, fc2_b + (size_t)ebase * CC, xmid, W, ebase, x, outp);
    }

    loss_kernel<<<1, 256, 0, stream>>>(et, stats, outp + NOUT);
}

// Round 21
// 1347.528 us; speedup vs baseline: 1.1862x; 1.0539x over previous
//
#include <hip/hip_runtime.h>
#include <hip/hip_bf16.h>

#define BB 8
#define SS 512
#define CC 768
#define HH 12
#define HD 64
#define EE 8
#define KK 2
#define MLPH 3072
#define NT (BB*SS)
#define NOUT (NT*CC)

#define SLOTB      68059136ull
#define SLOT_U16   34029568ull
#define SLOT_F32   17014784ull

typedef unsigned int u32;
typedef unsigned short u16;
typedef __attribute__((ext_vector_type(8))) short short8;
typedef __attribute__((ext_vector_type(4))) float f32x4;

__device__ __forceinline__ u16 f2bf(float f) {
    u32 u = __builtin_bit_cast(u32, f);
    u32 r = (u + 0x7fffu + ((u >> 16) & 1u)) >> 16;
    return (u16)r;
}
__device__ __forceinline__ float bf2f(u16 h) {
    u32 u = ((u32)h) << 16;
    return __builtin_bit_cast(float, u);
}
__device__ __forceinline__ void gl_lds16(const void* g, void* l) {
    __builtin_amdgcn_global_load_lds(
        (const __attribute__((address_space(1))) u32*)g,
        (__attribute__((address_space(3))) u32*)l, 16, 0, 0);
}
// XCD-band mapping: each XCD owns 4 consecutive row-blocks; col-major in band.
__device__ __forceinline__ void swz_rc(int bid, int& bm, int& bn) {
    int xcd = bid & 7, off = bid >> 3;
    bm = (xcd * 4 + (off & 3)) * 128;
    bn = (off >> 2) * 128;
}

// stage a 128x64 bf16 tile with 16B-chunk XOR swizzle on the SOURCE (m173), 256 threads
__device__ __forceinline__ void stage128x64(const u16* __restrict__ G, size_t ldg,
                                            u16* s, int tid)
{
    int wid = tid >> 6, lane = tid & 63;
#pragma unroll
    for (int it = 0; it < 4; ++it) {
        int cb = it * 256 + wid * 64;
        int c = cb + lane;
        int row = c >> 3;
        int ch = (c & 7) ^ (row & 7);
        gl_lds16(G + (size_t)row * ldg + ch * 8, s + cb * 8);
    }
}
__device__ __forceinline__ short8 frag64(const u16* s, int row, int kc, int lb) {
    int ch = (kc * 4 + lb) ^ (row & 7);
    return *(const short8*)(s + row * 64 + ch * 8);
}

// deep-pipe staging: one 128x32 A-tile + one 128x32 B-tile; 4 vmem instr per wave
__device__ __forceinline__ void stg_dp(const u16* __restrict__ A, const u16* __restrict__ B,
                                       int ldk, u16* sA, u16* sB, int t, int tid)
{
    int wid = tid >> 6, lane = tid & 63;
#pragma unroll
    for (int rd = 0; rd < 2; rd++) {
        int cb = rd * 256 + wid * 64;
        int c = cb + lane;
        gl_lds16(A + (size_t)(c >> 2) * ldk + t * 32 + (c & 3) * 8, sA + cb * 8);
    }
#pragma unroll
    for (int rd = 0; rd < 2; rd++) {
        int cb = rd * 256 + wid * 64;
        int c = cb + lane;
        gl_lds16(B + (size_t)(c >> 2) * ldk + t * 32 + (c & 3) * 8, sB + cb * 8);
    }
}

// ---------------- Router ----------------
__global__ __launch_bounds__(256) void router_kernel(const float* __restrict__ x,
    const float* __restrict__ et, float* __restrict__ W, float* __restrict__ stats)
{
    __shared__ float etl[EE * CC];
    __shared__ float pred[4][2 * EE];
    int tid = threadIdx.x;
    for (int i = tid; i < EE * CC; i += 256) etl[i] = et[i];
    __syncthreads();
    int wid = tid >> 6, lane = tid & 63;
    float psum[EE] = {}, csum[EE] = {};
    for (int i = 0; i < 2; i++) {
        int t = blockIdx.x * 8 + wid * 2 + i;
        const float* xr = x + (size_t)t * CC;
        float acc[EE] = {};
        for (int c = lane; c < CC; c += 64) {
            float xv = xr[c];
#pragma unroll
            for (int e = 0; e < EE; e++) acc[e] += xv * etl[e * CC + c];
        }
#pragma unroll
        for (int e = 0; e < EE; e++)
            for (int off = 1; off < 64; off <<= 1) acc[e] += __shfl_xor(acc[e], off, 64);
        if (lane == 0) {
            const float inv = 0.03608439182435161f;
            float l[EE], m = -1e30f;
#pragma unroll
            for (int e = 0; e < EE; e++) { l[e] = acc[e] * inv; m = fmaxf(m, l[e]); }
            float p[EE], sum = 0.f;
#pragma unroll
            for (int e = 0; e < EE; e++) { p[e] = __expf(l[e] - m); sum += p[e]; }
            int i1 = 0;
#pragma unroll
            for (int e = 1; e < EE; e++) if (p[e] > p[i1]) i1 = e;
            int i2 = -1;
#pragma unroll
            for (int e = 0; e < EE; e++) if (e != i1 && (i2 < 0 || p[e] > p[i2])) i2 = e;
            float wn = p[i1] + p[i2];
#pragma unroll
            for (int e = 0; e < EE; e++) W[t * EE + e] = 0.f;
            W[t * EE + i1] = p[i1] / wn;
            W[t * EE + i2] = p[i2] / wn;
#pragma unroll
            for (int e = 0; e < EE; e++) psum[e] += p[e] / sum;
            csum[i1] += 1.f; csum[i2] += 1.f;
        }
    }
    if (lane == 0) {
#pragma unroll
        for (int e = 0; e < EE; e++) { pred[wid][e] = psum[e]; pred[wid][EE + e] = csum[e]; }
    }
    __syncthreads();
    if (tid < 2 * EE) {
        float s = pred[0][tid] + pred[1][tid] + pred[2][tid] + pred[3][tid];
        atomicAdd(&stats[tid], s);
    }
}

// ---------------- plain LayerNorm (affine folded), batched over y ----------------
template<int MODE>
__global__ __launch_bounds__(256) void ln_kernel(const float* __restrict__ x, size_t xslot,
    u16* __restrict__ out_hi, u16* __restrict__ out_lo, size_t oslot)
{
    int t = blockIdx.x;
    int eb = blockIdx.y;
    const float* xr = x + (size_t)eb * xslot + (size_t)t * CC;
    __shared__ float red[256];
    int tid = threadIdx.x;
    float v[3];
    float s = 0.f;
#pragma unroll
    for (int i = 0; i < 3; i++) { v[i] = xr[tid + i * 256]; s += v[i]; }
    red[tid] = s; __syncthreads();
    for (int off = 128; off > 0; off >>= 1) { if (tid < off) red[tid] += red[tid + off]; __syncthreads(); }
    float mu = red[0] / (float)CC;
    __syncthreads();
    float s2 = 0.f;
#pragma unroll
    for (int i = 0; i < 3; i++) { float d = v[i] - mu; s2 += d * d; }
    red[tid] = s2; __syncthreads();
    for (int off = 128; off > 0; off >>= 1) { if (tid < off) red[tid] += red[tid + off]; __syncthreads(); }
    float var = red[0] / (float)CC;
    float sc = rsqrtf(var + 1e-5f);
#pragma unroll
    for (int i = 0; i < 3; i++) {
        int c = tid + i * 256;
        float val = (v[i] - mu) * sc;
        u16 hi = f2bf(val);
        out_hi[(size_t)eb * oslot + (size_t)t * CC + c] = hi;
        if (MODE) out_lo[(size_t)eb * oslot + (size_t)t * CC + c] = f2bf(val - bf2f(hi));
    }
}

// ---------------- per-expert weight prep, batched over y ----------------
__global__ __launch_bounds__(256) void prep_expert(
    const float* __restrict__ qkv_w0, const float* __restrict__ qkv_b0,
    const float* __restrict__ proj_w0,
    const float* __restrict__ fc1_w0, const float* __restrict__ fc1_b0,
    const float* __restrict__ fc2_w0,
    const float* __restrict__ g1_0, const float* __restrict__ b1_0,
    const float* __restrict__ g2_0, const float* __restrict__ b2_0,
    u16* __restrict__ qkvTh, u16* __restrict__ qkvTl,
    u16* __restrict__ projT, u16* __restrict__ fc1T, u16* __restrict__ fc2T,
    float* __restrict__ biasq, float* __restrict__ biasf1, int ebase)
{
    __shared__ float tile[32][33];
    __shared__ float bsh[CC];
    __shared__ float redg[256];
    int bid = blockIdx.x;
    int eb = blockIdx.y;
    int ge = ebase + eb;
    int tid = threadIdx.x;
    const float* qkv_w = qkv_w0 + (size_t)ge * CC * 3 * CC;
    const float* qkv_b = qkv_b0 + (size_t)ge * 3 * CC;
    const float* proj_w = proj_w0 + (size_t)ge * CC * CC;
    const float* fc1_w = fc1_w0 + (size_t)ge * CC * MLPH;
    const float* fc1_b = fc1_b0 + (size_t)ge * MLPH;
    const float* fc2_w = fc2_w0 + (size_t)ge * MLPH * CC;
    const float* g1 = g1_0 + (size_t)ge * CC;
    const float* b1 = b1_0 + (size_t)ge * CC;
    const float* g2 = g2_0 + (size_t)ge * CC;
    const float* b2 = b2_0 + (size_t)ge * CC;

    if (bid < 6912) {
        const float* src; const float* scale = nullptr;
        u16 *dh, *dl = nullptr; int N, Kd, n0, k0;
        if (bid < 1728) {
            src = qkv_w; scale = g1;
            dh = qkvTh + (size_t)eb * SLOT_U16; dl = qkvTl + (size_t)eb * SLOT_U16;
            N = 2304; Kd = 768; n0 = (bid % 72) * 32; k0 = (bid / 72) * 32;
        } else if (bid < 2304) {
            int i = bid - 1728;
            src = proj_w; dh = projT + (size_t)eb * SLOT_U16; N = 768; Kd = 768;
            n0 = (i % 24) * 32; k0 = (i / 24) * 32;
        } else if (bid < 4608) {
            int i = bid - 2304;
            src = fc1_w; scale = g2; dh = fc1T + (size_t)eb * SLOT_U16; N = 3072; Kd = 768;
            n0 = (i % 96) * 32; k0 = (i / 96) * 32;
        } else {
            int i = bid - 4608;
            src = fc2_w; dh = fc2T + (size_t)eb * SLOT_U16; N = 768; Kd = 3072;
            n0 = (i % 24) * 32; k0 = (i / 24) * 32;
        }
        int tx = tid & 31, ty = tid >> 5;
#pragma unroll
        for (int i = 0; i < 32; i += 8) {
            float v = src[(size_t)(k0 + ty + i) * N + n0 + tx];
            if (scale) v *= scale[k0 + ty + i];
            tile[ty + i][tx] = v;
        }
        __syncthreads();
#pragma unroll
        for (int i = 0; i < 32; i += 8) {
            float v = tile[tx][ty + i];
            u16 hi = f2bf(v);
            dh[(size_t)(n0 + ty + i) * Kd + k0 + tx] = hi;
            if (dl) dl[(size_t)(n0 + ty + i) * Kd + k0 + tx] = f2bf(v - bf2f(hi));
        }
    } else {
        const float* bv; const float* wsrc; const float* badd;
        float* dst; int N, n0;
        if (bid < 6984) { bv = b1; wsrc = qkv_w; badd = qkv_b; dst = biasq + (size_t)eb * SLOT_F32; N = 2304; n0 = (bid - 6912) * 32; }
        else            { bv = b2; wsrc = fc1_w; badd = fc1_b; dst = biasf1 + (size_t)eb * SLOT_F32; N = MLPH; n0 = (bid - 6984) * 32; }
        for (int i = tid; i < CC; i += 256) bsh[i] = bv[i];
        __syncthreads();
        int g = tid & 31, l8 = tid >> 5;
        int n = n0 + g;
        float acc = 0.f;
        for (int k = l8; k < CC; k += 8) acc += bsh[k] * wsrc[(size_t)k * N + n];
        redg[tid] = acc; __syncthreads();
        if (tid < 32) {
            float sum = 0.f;
#pragma unroll
            for (int i = 0; i < 8; i++) sum += redg[tid + i * 32];
            dst[n0 + tid] = sum + badd[n0 + tid];
        }
    }
}

// ---------------- qkv GEMM, BK=64: split-precision GEMM; hi-only q/k store; coalesced V ----------------
__global__ __launch_bounds__(256) void gemm_qkv_bk64(
    const u16* __restrict__ Ah, const u16* __restrict__ Al,
    const u16* __restrict__ Bh0, const u16* __restrict__ Bl0,
    const float* __restrict__ biasq0, u16* __restrict__ qk_hi0,
    u16* __restrict__ vraw0)
{
    __shared__ __align__(16) u16 sAh[128 * 64], sAl[128 * 64];
    __shared__ __align__(16) u16 sBh[128 * 64], sBl[128 * 64];
    int tid = threadIdx.x;
    int eb = blockIdx.y;
    int bm, bn;
    swz_rc(blockIdx.x, bm, bn);
    bool qk_tile = (bn < 1536);
    int wid = tid >> 6, lane = tid & 63;
    int wr = wid >> 1, wc = wid & 1;
    int la = lane & 15, lb = lane >> 4;
    const u16* Bh = Bh0 + (size_t)eb * SLOT_U16;
    const u16* Bl = Bl0 + (size_t)eb * SLOT_U16;
    const float* bias = biasq0 + (size_t)eb * SLOT_F32;
    u16* qk_hi = qk_hi0 + (size_t)eb * SLOT_U16;
    u16* vraw = vraw0 + (size_t)eb * SLOT_U16;

    f32x4 acc[4][4];
#pragma unroll
    for (int i = 0; i < 4; i++)
#pragma unroll
        for (int j = 0; j < 4; j++) acc[i][j] = (f32x4){0.f, 0.f, 0.f, 0.f};

    const u16* Abh = Ah + (size_t)bm * CC;
    const u16* Abl = Al + (size_t)bm * CC;
    const u16* Bbh = Bh + (size_t)bn * CC;
    const u16* Bbl = Bl + (size_t)bn * CC;
    for (int k0 = 0; k0 < CC; k0 += 64) {
        stage128x64(Abh + k0, CC, sAh, tid);
        stage128x64(Bbh + k0, CC, sBh, tid);
        if (qk_tile) {
            stage128x64(Abl + k0, CC, sAl, tid);
            stage128x64(Bbl + k0, CC, sBl, tid);
        }
        __syncthreads();
        if (qk_tile) {
#pragma unroll
            for (int kc = 0; kc < 2; kc++) {
                short8 avh[4], avl[4], bvh[4], bvl[4];
#pragma unroll
                for (int i = 0; i < 4; i++) {
                    int row = wr * 64 + i * 16 + la;
                    avh[i] = frag64(sAh, row, kc, lb);
                    avl[i] = frag64(sAl, row, kc, lb);
                }
#pragma unroll
                for (int j = 0; j < 4; j++) {
                    int row = wc * 64 + j * 16 + la;
                    bvh[j] = frag64(sBh, row, kc, lb);
                    bvl[j] = frag64(sBl, row, kc, lb);
                }
#pragma unroll
                for (int i = 0; i < 4; i++)
#pragma unroll
                    for (int j = 0; j < 4; j++) {
                        acc[i][j] = __builtin_amdgcn_mfma_f32_16x16x32_bf16(avh[i], bvh[j], acc[i][j], 0, 0, 0);
                        acc[i][j] = __builtin_amdgcn_mfma_f32_16x16x32_bf16(avh[i], bvl[j], acc[i][j], 0, 0, 0);
                        acc[i][j] = __builtin_amdgcn_mfma_f32_16x16x32_bf16(avl[i], bvh[j], acc[i][j], 0, 0, 0);
                    }
            }
        } else {
#pragma unroll
            for (int kc = 0; kc < 2; kc++) {
                short8 avh[4], bvh[4];
#pragma unroll
                for (int i = 0; i < 4; i++) avh[i] = frag64(sAh, wr * 64 + i * 16 + la, kc, lb);
#pragma unroll
                for (int j = 0; j < 4; j++) bvh[j] = frag64(sBh, wc * 64 + j * 16 + la, kc, lb);
#pragma unroll
                for (int i = 0; i < 4; i++)
#pragma unroll
                    for (int j = 0; j < 4; j++)
                        acc[i][j] = __builtin_amdgcn_mfma_f32_16x16x32_bf16(avh[i], bvh[j], acc[i][j], 0, 0, 0);
            }
        }
        __syncthreads();
    }
#pragma unroll
    for (int i = 0; i < 4; i++) {
#pragma unroll
        for (int j = 0; j < 4; j++) {
            int gn = bn + wc * 64 + j * 16 + la;
            float bsv = bias[gn];
#pragma unroll
            for (int r = 0; r < 4; r++) {
                int gm = bm + wr * 64 + i * 16 + lb * 4 + r;
                float v = acc[i][j][r] + bsv;
                if (qk_tile) {
                    qk_hi[(size_t)gm * 1536 + gn] = f2bf(v);
                } else {
                    vraw[(size_t)gm * CC + (gn - 1536)] = f2bf(v);   // coalesced
                }
            }
        }
    }
}

// ---------------- V transpose: vraw [4096][768] -> vt [b*H+h][d][s] ----------------
__global__ __launch_bounds__(256) void vtrans(const u16* __restrict__ vraw0,
    u16* __restrict__ vt0)
{
    __shared__ u16 tile[64][65];
    int st = blockIdx.x;                 // s-tile 0..7
    int h = blockIdx.y;
    int z = blockIdx.z;
    int b = z & (BB - 1), eb = z >> 3;
    const u16* vraw = vraw0 + (size_t)eb * SLOT_U16;
    u16* vt = vt0 + (size_t)eb * SLOT_U16;
    int tid = threadIdx.x;
    int row = tid >> 3, ch = tid & 7;
#pragma unroll
    for (int it = 0; it < 2; it++) {
        int s = it * 32 + row;
        const u16* src = vraw + (size_t)(b * SS + st * 64 + s) * CC + h * HD + ch * 8;
        short8 v = *(const short8*)src;
#pragma unroll
        for (int k = 0; k < 8; k++) tile[s][ch * 8 + k] = (u16)v[k];
    }
    __syncthreads();
#pragma unroll
    for (int it = 0; it < 2; it++) {
        int d = it * 32 + row;
        u16* dst = vt + ((size_t)((b * HH + h) * HD + d)) * SS + st * 64 + ch * 8;
        short8 v;
#pragma unroll
        for (int k = 0; k < 8; k++) v[k] = (short)tile[ch * 8 + k][d];
        *(short8*)dst = v;
    }
}

// ---------------- deep-pipe GEMM body: 128x128, BK=32, 3-buf, counted vmcnt ----------------
template<int EPI>
__device__ __forceinline__ void gemm_dp_body(
    const u16* __restrict__ Ab, const u16* __restrict__ Bb, int Kdim,
    const float* __restrict__ biasp, const float* __restrict__ resp,
    const float* __restrict__ Wt, int ge, const float* __restrict__ xinit,
    void* __restrict__ Cout, int N, int bm, int bn)
{
    __shared__ __align__(16) u16 sA[3][128 * 32];
    __shared__ __align__(16) u16 sB[3][128 * 32];
    int tid = threadIdx.x;
    int wid = tid >> 6, lane = tid & 63;
    int wr = wid >> 1, wc = wid & 1;
    int la = lane & 15, lb = lane >> 4;
    int NTILE = Kdim / 32;

    f32x4 acc[4][4];
#pragma unroll
    for (int i = 0; i < 4; i++)
#pragma unroll
        for (int j = 0; j < 4; j++) acc[i][j] = (f32x4){0.f, 0.f, 0.f, 0.f};

    stg_dp(Ab, Bb, Kdim, sA[0], sB[0], 0, tid);
    stg_dp(Ab, Bb, Kdim, sA[1], sB[1], 1, tid);

    for (int t = 0; t < NTILE; t++) {
        if (t < NTILE - 1) asm volatile("s_waitcnt vmcnt(4)" ::: "memory");
        else               asm volatile("s_waitcnt vmcnt(0)" ::: "memory");
        __builtin_amdgcn_s_barrier();
        asm volatile("" ::: "memory");

        const u16* cA = &sA[t % 3][0];
        const u16* cB = &sB[t % 3][0];
        __builtin_amdgcn_s_setprio(1);
        short8 bv[4];
#pragma unroll
        for (int j = 0; j < 4; j++)
            bv[j] = *(const short8*)(cB + ((size_t)(wc * 64 + j * 16 + la) * 4 + lb) * 8);
#pragma unroll
        for (int i = 0; i < 4; i++) {
            short8 av = *(const short8*)(cA + ((size_t)(wr * 64 + i * 16 + la) * 4 + lb) * 8);
#pragma unroll
            for (int j = 0; j < 4; j++)
                acc[i][j] = __builtin_amdgcn_mfma_f32_16x16x32_bf16(av, bv[j], acc[i][j], 0, 0, 0);
        }
        __builtin_amdgcn_s_setprio(0);

        if (t + 2 < NTILE) stg_dp(Ab, Bb, Kdim, sA[(t + 2) % 3], sB[(t + 2) % 3], t + 2, tid);
    }

#pragma unroll
    for (int i = 0; i < 4; i++) {
#pragma unroll
        for (int j = 0; j < 4; j++) {
            int gn = bn + wc * 64 + j * 16 + la;
            float bsv = biasp[gn];
#pragma unroll
            for (int r = 0; r < 4; r++) {
                int gm = bm + wr * 64 + i * 16 + lb * 4 + r;
                size_t idx = (size_t)gm * N + gn;
                float v = acc[i][j][r] + bsv;
                if (EPI == 1) {
                    ((float*)Cout)[idx] = resp[idx] + v;
                } else if (EPI == 2) {
                    float gel = 0.5f * v * (1.0f + erff(v * 0.70710678118654752f));
                    ((u16*)Cout)[idx] = f2bf(gel);
                } else {
                    float w = Wt[(size_t)gm * EE + ge];
                    float val = w * (v + resp[idx]);
                    if (ge == 0) val += xinit[idx];
                    atomicAdd(&((float*)Cout)[idx], val);
                }
            }
        }
    }
}

// proj: A=obf [4096][768], B=projT [768][768] -> xmid f32; grid (192, EB)
__global__ __launch_bounds__(256) void gemm_proj_dp(
    const u16* __restrict__ A0, const u16* __restrict__ BT0,
    const float* __restrict__ bias0, const float* __restrict__ x,
    float* __restrict__ C0)
{
    int eb = blockIdx.y;
    int bm, bn;
    swz_rc(blockIdx.x, bm, bn);
    gemm_dp_body<1>(A0 + (size_t)eb * SLOT_U16 + (size_t)bm * CC,
                    BT0 + (size_t)eb * SLOT_U16 + (size_t)bn * CC, CC,
                    bias0 + (size_t)eb * CC, x, nullptr, 0, nullptr,
                    C0 + (size_t)eb * SLOT_F32, CC, bm, bn);
}

// fc1: grid (768, EB)
__global__ __launch_bounds__(256) void gemm_fc1_dp(
    const u16* __restrict__ A0, const u16* __restrict__ BT0,
    const float* __restrict__ bias0, u16* __restrict__ C0)
{
    int eb = blockIdx.y;
    int bm, bn;
    swz_rc(blockIdx.x, bm, bn);
    gemm_dp_body<2>(A0 + (size_t)eb * SLOT_U16 + (size_t)bm * CC,
                    BT0 + (size_t)eb * SLOT_U16 + (size_t)bn * CC, CC,
                    bias0 + (size_t)eb * SLOT_F32, nullptr, nullptr, 0, nullptr,
                    C0 + (size_t)eb * SLOT_U16, MLPH, bm, bn);
}

// fc2: grid (192, EB)
__global__ __launch_bounds__(256) void gemm_fc2_dp(
    const u16* __restrict__ A0, const u16* __restrict__ BT0,
    const float* __restrict__ bias0, const float* __restrict__ res0,
    const float* __restrict__ Wt, int ebase, const float* __restrict__ xinit,
    float* __restrict__ Cout)
{
    int eb = blockIdx.y;
    int bm, bn;
    swz_rc(blockIdx.x, bm, bn);
    gemm_dp_body<5>(A0 + (size_t)eb * SLOT_U16 + (size_t)bm * MLPH,
                    BT0 + (size_t)eb * SLOT_U16 + (size_t)bn * MLPH, MLPH,
                    bias0 + (size_t)eb * CC, res0 + (size_t)eb * SLOT_F32,
                    Wt, ebase + eb, xinit, Cout, CC, bm, bn);
}

// ---------------- MFMA flash attention, 1-term QK^T (R2-calibrated), single-buffer ----------------
__global__ __launch_bounds__(256) void attn_mfma(const u16* __restrict__ qk_hi0,
    const u16* __restrict__ vt0, u16* __restrict__ o0)
{
    int q0 = blockIdx.x * 64;
    int h = blockIdx.y;
    int z = blockIdx.z;
    int b = z & (BB - 1), eb = z >> 3;
    int tid = threadIdx.x, wid = tid >> 6, lane = tid & 63;
    int la = lane & 15, lb = lane >> 4;
    __shared__ __align__(16) u16 Ksh[64 * 64];
    __shared__ __align__(16) u16 Vs[64 * 64];
    __shared__ __align__(16) u16 Ps[4][16 * 64];

    const u16* qk_hi = qk_hi0 + (size_t)eb * SLOT_U16;
    const u16* vt = vt0 + (size_t)eb * SLOT_U16;
    u16* o = o0 + (size_t)eb * SLOT_U16;

    short8 aqh[2];
    {
        size_t qoff = (size_t)(b * SS + q0 + wid * 16 + la) * 1536 + h * HD;
#pragma unroll
        for (int kc = 0; kc < 2; kc++)
            aqh[kc] = *(const short8*)(qk_hi + qoff + kc * 32 + lb * 8);
    }
    const u16* kbh = qk_hi + (size_t)(b * SS) * 1536 + CC + h * HD;
    const u16* vtbase = vt + (size_t)((b * HH + h) * HD) * SS;

    float m_r[4], l_r[4];
    f32x4 acc_o[4];
#pragma unroll
    for (int r = 0; r < 4; r++) { m_r[r] = -1e30f; l_r[r] = 0.f; }
#pragma unroll
    for (int d0 = 0; d0 < 4; d0++) acc_o[d0] = (f32x4){0.f, 0.f, 0.f, 0.f};

    for (int kt = 0; kt < SS; kt += 64) {
#pragma unroll
        for (int it = 0; it < 2; it++) {
            int base = it * 256 + wid * 64;
            int c = base + lane;
            int row = c >> 3;
            int gk = (c & 7) ^ (row & 7);
            gl_lds16(kbh + (size_t)(kt + row) * 1536 + gk * 8, Ksh + base * 8);
            gl_lds16(vtbase + (size_t)row * SS + kt + gk * 8, Vs + base * 8);
        }
        __syncthreads();

        f32x4 s4[4];
#pragma unroll
        for (int j = 0; j < 4; j++) s4[j] = (f32x4){0.f, 0.f, 0.f, 0.f};
#pragma unroll
        for (int kc = 0; kc < 2; kc++)
#pragma unroll
            for (int j = 0; j < 4; j++) {
                size_t off = (size_t)(j * 16 + la) * 64 + (((kc * 4 + lb) ^ (la & 7)) * 8);
                short8 bkh = *(const short8*)(Ksh + off);
                s4[j] = __builtin_amdgcn_mfma_f32_16x16x32_bf16(aqh[kc], bkh, s4[j], 0, 0, 0);
            }
#pragma unroll
        for (int j = 0; j < 4; j++) s4[j] = s4[j] * 8.f;

#pragma unroll
        for (int r = 0; r < 4; r++) {
            float mx = fmaxf(fmaxf(s4[0][r], s4[1][r]), fmaxf(s4[2][r], s4[3][r]));
#pragma unroll
            for (int off = 1; off < 16; off <<= 1) mx = fmaxf(mx, __shfl_xor(mx, off, 64));
            float mn = fmaxf(m_r[r], mx);
            float corr = __expf(m_r[r] - mn);
            m_r[r] = mn;
            float rs = 0.f;
#pragma unroll
            for (int j = 0; j < 4; j++) {
                float p = __expf(s4[j][r] - mn);
                s4[j][r] = p; rs += p;
            }
#pragma unroll
            for (int off = 1; off < 16; off <<= 1) rs += __shfl_xor(rs, off, 64);
            l_r[r] = l_r[r] * corr + rs;
#pragma unroll
            for (int d0 = 0; d0 < 4; d0++) acc_o[d0][r] = acc_o[d0][r] * corr;
        }
#pragma unroll
        for (int j = 0; j < 4; j++)
#pragma unroll
            for (int r = 0; r < 4; r++) {
                int row = lb * 4 + r;
                int sg = (2 * j + (la >> 3)) ^ (row & 7);
                Ps[wid][row * 64 + sg * 8 + (la & 7)] = f2bf(s4[j][r]);
            }
        short8 pa[2];
#pragma unroll
        for (int kc = 0; kc < 2; kc++)
            pa[kc] = *(const short8*)(&Ps[wid][la * 64 + (((kc * 4 + lb) ^ (la & 7)) * 8)]);
#pragma unroll
        for (int d0 = 0; d0 < 4; d0++)
#pragma unroll
            for (int kc = 0; kc < 2; kc++) {
                short8 bv = *(const short8*)(&Vs[(d0 * 16 + la) * 64 + (((kc * 4 + lb) ^ (la & 7)) * 8)]);
                acc_o[d0] = __builtin_amdgcn_mfma_f32_16x16x32_bf16(pa[kc], bv, acc_o[d0], 0, 0, 0);
            }
        __syncthreads();
    }
#pragma unroll
    for (int r = 0; r < 4; r++) {
        float invl = 1.f / l_r[r];
        int tok = b * SS + q0 + wid * 16 + lb * 4 + r;
#pragma unroll
        for (int d0 = 0; d0 < 4; d0++)
            o[(size_t)tok * CC + h * HD + d0 * 16 + la] = f2bf(acc_o[d0][r] * invl);
    }
}

// ---------------- balance loss ----------------
__global__ __launch_bounds__(256) void loss_kernel(const float* __restrict__ et,
    const float* __restrict__ stats, float* __restrict__ out_loss)
{
    __shared__ float red[256];
    int tid = threadIdx.x;
    float s = 0.f;
    for (int i = tid; i < EE * CC; i += 256) { float v = et[i]; s += v * v; }
    red[tid] = s; __syncthreads();
    for (int off = 128; off > 0; off >>= 1) { if (tid < off) red[tid] += red[tid + off]; __syncthreads(); }
    if (tid == 0) {
        float bl = 0.f;
        for (int e = 0; e < EE; e++) {
            float f = stats[EE + e] / (float)(NT * KK);
            float P = stats[e] / (float)NT;
            bl += f * P;
        }
        *out_loss = (float)EE * bl + 0.01f * sqrtf(red[0]);
    }
}

extern "C" void kernel_launch(void* const* d_in, const int* in_sizes, int n_in,
                              void* d_out, int out_size, void* d_ws, size_t ws_size,
                              hipStream_t stream) {
    const float* x      = (const float*)d_in[0];
    const float* et     = (const float*)d_in[1];
    const float* ln1_g  = (const float*)d_in[2];
    const float* ln1_b  = (const float*)d_in[3];
    const float* qkv_w  = (const float*)d_in[4];
    const float* qkv_b  = (const float*)d_in[5];
    const float* proj_w = (const float*)d_in[6];
    const float* proj_b = (const float*)d_in[7];
    const float* ln2_g  = (const float*)d_in[8];
    const float* ln2_b  = (const float*)d_in[9];
    const float* fc1_w  = (const float*)d_in[10];
    const float* fc1_b  = (const float*)d_in[11];
    const float* fc2_w  = (const float*)d_in[12];
    const float* fc2_b  = (const float*)d_in[13];
    float* outp = (float*)d_out;
    char* base = (char*)d_ws;

    const size_t FIXED = 12714496;
    int EB = 1;
    if (ws_size >= FIXED + 8 * SLOTB) EB = 8;
    else if (ws_size >= FIXED + 4 * SLOTB) EB = 4;
    else if (ws_size >= FIXED + 2 * SLOTB) EB = 2;

    float* W      = (float*)(base);
    float* stats  = (float*)(base + 131072);
    u16*   xh_hi  = (u16*)  (base + 131584);
    u16*   xh_lo  = (u16*)  (base + 6423040);
    char* slot0 = base + FIXED;
    u16*   qkvTh  = (u16*)  (slot0);
    u16*   qkvTl  = (u16*)  (slot0 + 3538944);
    u16*   projT  = (u16*)  (slot0 + 7077888);
    u16*   fc1T   = (u16*)  (slot0 + 8257536);
    u16*   fc2T   = (u16*)  (slot0 + 12976128);
    float* biasq  = (float*)(slot0 + 17694720);
    float* biasf1 = (float*)(slot0 + 17711104);
    u16*   qk_hi  = (u16*)  (slot0 + 17727488);
    u16*   mlp1   = (u16*)  (slot0 + 17727488);   // aliases qk_hi(+dead lo region)
    u16*   vtb    = (u16*)  (slot0 + 42893312);
    u16*   xmhat  = (u16*)  (slot0 + 42893312);   // aliases vt (dead after attn)
    u16*   obf    = (u16*)  (slot0 + 49184768);
    u16*   vraw   = obf;                          // aliases obf (dead before attn writes it)
    float* xmid   = (float*)(slot0 + 55476224);

    hipMemsetAsync(stats, 0, 16 * sizeof(float), stream);
    hipMemsetAsync(outp, 0, (size_t)NOUT * sizeof(float), stream);

    router_kernel<<<NT / 8, 256, 0, stream>>>(x, et, W, stats);
    ln_kernel<1><<<dim3(NT, 1), 256, 0, stream>>>(x, 0, xh_hi, xh_lo, 0);

    for (int ebase = 0; ebase < EE; ebase += EB) {
        prep_expert<<<dim3(7080, EB), 256, 0, stream>>>(
            qkv_w, qkv_b, proj_w, fc1_w, fc1_b, fc2_w,
            ln1_g, ln1_b, ln2_g, ln2_b,
            qkvTh, qkvTl, projT, fc1T, fc2T, biasq, biasf1, ebase);

        gemm_qkv_bk64<<<dim3(18 * 32, EB), 256, 0, stream>>>(
            xh_hi, xh_lo, qkvTh, qkvTl, biasq, qk_hi, vraw);

        vtrans<<<dim3(SS / 64, HH, BB * EB), 256, 0, stream>>>(vraw, vtb);

        attn_mfma<<<dim3(SS / 64, HH, BB * EB), 256, 0, stream>>>(qk_hi, vtb, obf);

        gemm_proj_dp<<<dim3(6 * 32, EB), 256, 0, stream>>>(
            obf, projT, proj_b + (size_t)ebase * CC, x, xmid);

        ln_kernel<0><<<dim3(NT, EB), 256, 0, stream>>>(xmid, SLOT_F32, xmhat, nullptr, SLOT_U16);

        gemm_fc1_dp<<<dim3(24 * 32, EB), 256, 0, stream>>>(xmhat, fc1T, biasf1, mlp1);

        gemm_fc2_dp<<<dim3(6 * 32, EB), 256, 0, stream>>>(
            mlp1, fc2T, fc2_b + (size_t)ebase * CC, xmid, W, ebase, x, outp);
    }

    loss_kernel<<<1, 256, 0, stream>>>(et, stats, outp + NOUT);
}